// Round 1
// baseline (871.481 us; speedup 1.0000x reference)
//
#include <hip/hip_runtime.h>
#include <hip/hip_bf16.h>
#include <cstdint>

#define B_ 4
#define T_ 2048
#define C_ 1024
#define H_ 16
#define D_ 64

typedef __attribute__((ext_vector_type(8))) short bf16x8;
typedef __attribute__((ext_vector_type(4))) float f32x4;

static __device__ __forceinline__ unsigned short f2bf(float f) {
  unsigned u = __float_as_uint(f);
  u += 0x7fff + ((u >> 16) & 1);   // round-to-nearest-even
  return (unsigned short)(u >> 16);
}
static __device__ __forceinline__ float bf2f(unsigned short b) {
  return __uint_as_float(((unsigned)b) << 16);
}

// ---------------- f32 -> bf16 convert ----------------
__global__ __launch_bounds__(256) void cvt_kernel(const float* __restrict__ src,
                                                  unsigned short* __restrict__ dst, int n) {
  int i = (blockIdx.x * 256 + threadIdx.x) * 4;
  if (i >= n) return;
  float4 v = *reinterpret_cast<const float4*>(src + i);
  ushort4 o;
  o.x = f2bf(v.x); o.y = f2bf(v.y); o.z = f2bf(v.z); o.w = f2bf(v.w);
  *reinterpret_cast<ushort4*>(dst + i) = o;
}

// ---------------- bf16 GEMM: C[M,N] = A[M,K] * B[N,K]^T ----------------
// m97 structure: 128x128 tile, BK=32, 4 waves (2x2 of 64x64), 16x16x32 MFMA,
// global_load_lds width-16 staging, single LDS buffer, 2 barriers / K-step.
template<int OUT_BF16>
__global__ __launch_bounds__(256) void gemm_bt(const unsigned short* __restrict__ A,
                                               const unsigned short* __restrict__ Bw,
                                               void* __restrict__ Cp,
                                               int M, int N, int K) {
  __shared__ __align__(16) unsigned short sA[128 * 32];
  __shared__ __align__(16) unsigned short sB[128 * 32];
  const int tid = threadIdx.x;
  const int wid = tid >> 6, lane = tid & 63;
  const int wm = wid >> 1, wn = wid & 1;
  const long blockM = (long)blockIdx.y * 128;
  const long blockN = (long)blockIdx.x * 128;

  f32x4 acc[4][4] = {};

  // staging addresses: wave wid covers rows [wid*32, wid*32+32)
  const int ar = lane >> 2;            // row within 16-row chunk
  const int ac = (lane & 3) * 8;       // elem col offset (8 bf16 = 16B)
  const unsigned short* Abase = A + (blockM + wid * 32 + ar) * (long)K + ac;
  const unsigned short* Bbase = Bw + (blockN + wid * 32 + ar) * (long)K + ac;
  char* sAb = (char*)sA + wid * 2048;  // wave-uniform LDS dest
  char* sBb = (char*)sB + wid * 2048;

  for (int k0 = 0; k0 < K; k0 += 32) {
    __syncthreads();
    __builtin_amdgcn_global_load_lds((const __attribute__((address_space(1))) void*)(Abase + k0),
                                     (__attribute__((address_space(3))) void*)(sAb), 16, 0, 0);
    __builtin_amdgcn_global_load_lds((const __attribute__((address_space(1))) void*)(Abase + 16 * (long)K + k0),
                                     (__attribute__((address_space(3))) void*)(sAb + 1024), 16, 0, 0);
    __builtin_amdgcn_global_load_lds((const __attribute__((address_space(1))) void*)(Bbase + k0),
                                     (__attribute__((address_space(3))) void*)(sBb), 16, 0, 0);
    __builtin_amdgcn_global_load_lds((const __attribute__((address_space(1))) void*)(Bbase + 16 * (long)K + k0),
                                     (__attribute__((address_space(3))) void*)(sBb + 1024), 16, 0, 0);
    __syncthreads();

    const int koff = (lane >> 4) * 8;
    const int rA = wm * 64 + (lane & 15);
    const int rB = wn * 64 + (lane & 15);
    bf16x8 af[4], bfr[4];
#pragma unroll
    for (int m = 0; m < 4; ++m)
      af[m] = *reinterpret_cast<const bf16x8*>(&sA[(rA + m * 16) * 32 + koff]);
#pragma unroll
    for (int n = 0; n < 4; ++n)
      bfr[n] = *reinterpret_cast<const bf16x8*>(&sB[(rB + n * 16) * 32 + koff]);
#pragma unroll
    for (int m = 0; m < 4; ++m)
#pragma unroll
      for (int n = 0; n < 4; ++n)
        acc[m][n] = __builtin_amdgcn_mfma_f32_16x16x32_bf16(af[m], bfr[n], acc[m][n], 0, 0, 0);
  }

  // C write: D frag mapping col=lane&15, row=(lane>>4)*4+reg
  const int cr = (lane >> 4) * 4;
  const int cc = lane & 15;
#pragma unroll
  for (int m = 0; m < 4; ++m) {
    long R = blockM + wm * 64 + m * 16 + cr;
#pragma unroll
    for (int n = 0; n < 4; ++n) {
      long Cc = blockN + wn * 64 + n * 16 + cc;
#pragma unroll
      for (int r = 0; r < 4; ++r) {
        if (OUT_BF16)
          ((unsigned short*)Cp)[(R + r) * (long)N + Cc] = f2bf(acc[m][n][r]);
        else
          ((float*)Cp)[(R + r) * (long)N + Cc] = acc[m][n][r];
      }
    }
  }
}

// ---------------- sequential scan ----------------
// Rows of S are independent: s_d <- s_d + (beta*v_d - alpha*(s_d.k)/||k||) * k/||k||
// Block: 16 rows x 16 lanes/row (4 cols each). 256 blocks = (B*H) x 4 rowgroups.
__global__ __launch_bounds__(256) void scan_kernel(const unsigned short* __restrict__ qkv,
                                                   const float* __restrict__ alpha_raw,
                                                   const float* __restrict__ beta_raw,
                                                   const float* __restrict__ state_in,
                                                   unsigned short* __restrict__ y,
                                                   float* __restrict__ state_out) {
  const int blk = blockIdx.x;
  const int bh = blk >> 2, rg = blk & 3;
  const int b = bh >> 4, h = bh & 15;
  const int tid = threadIdx.x;
  const int lr = tid >> 4, cg = tid & 15;
  const int row = rg * 16 + lr;
  const int c0 = cg * 4;

  float s0, s1, s2, s3;
  {
    float4 si = *reinterpret_cast<const float4*>(state_in + ((long)bh * D_ + row) * D_ + c0);
    s0 = si.x; s1 = si.y; s2 = si.z; s3 = si.w;
  }
  const float alpha = 0.5f / (1.f + __expf(-alpha_raw[h]));
  const float beta  = 0.5f / (1.f + __expf(-beta_raw[h]));

  const unsigned short* qp = qkv + (long)b * T_ * 3072 + h * 64 + c0;
  const unsigned short* kp = qp + 1024;
  const unsigned short* vp = qkv + (long)b * T_ * 3072 + 2048 + h * 64 + row;
  unsigned short* yp = y + (long)b * T_ * 1024 + h * 64 + row;

  ushort4 q4 = *(const ushort4*)qp;
  ushort4 k4 = *(const ushort4*)kp;
  unsigned short vs = *vp;

  for (int t = 0; t < T_; ++t) {
    ushort4 q4n, k4n; unsigned short vsn;
    if (t + 1 < T_) {  // prefetch next step (state is the only serial dep)
      q4n = *(const ushort4*)(qp + (long)(t + 1) * 3072);
      k4n = *(const ushort4*)(kp + (long)(t + 1) * 3072);
      vsn = *(vp + (long)(t + 1) * 3072);
    }
    float q0 = bf2f(q4.x), q1 = bf2f(q4.y), q2 = bf2f(q4.z), q3 = bf2f(q4.w);
    float k0 = bf2f(k4.x), k1 = bf2f(k4.y), k2 = bf2f(k4.z), k3 = bf2f(k4.w);
    float vf = bf2f(vs);
    float py = s0 * q0 + s1 * q1 + s2 * q2 + s3 * q3;
    float pk = s0 * k0 + s1 * k1 + s2 * k2 + s3 * k3;
    float ps = k0 * k0 + k1 * k1 + k2 * k2 + k3 * k3;
#pragma unroll
    for (int m = 1; m < 16; m <<= 1) {
      py += __shfl_xor(py, m);
      pk += __shfl_xor(pk, m);
      ps += __shfl_xor(ps, m);
    }
    float inv = 1.f / fmaxf(sqrtf(ps), 1e-12f);
    if (cg == 0) yp[(long)t * 1024] = f2bf(py);
    float coef = (beta * vf - alpha * pk * inv) * inv;
    s0 = fmaf(coef, k0, s0);
    s1 = fmaf(coef, k1, s1);
    s2 = fmaf(coef, k2, s2);
    s3 = fmaf(coef, k3, s3);
    q4 = q4n; k4 = k4n; vs = vsn;
  }
  float4 so; so.x = s0; so.y = s1; so.z = s2; so.w = s3;
  *reinterpret_cast<float4*>(state_out + ((long)bh * D_ + row) * D_ + c0) = so;
}

// ---------------- launch ----------------
extern "C" void kernel_launch(void* const* d_in, const int* in_sizes, int n_in,
                              void* d_out, int out_size, void* d_ws, size_t ws_size,
                              hipStream_t stream) {
  (void)in_sizes; (void)n_in; (void)out_size; (void)ws_size;
  const float* x     = (const float*)d_in[0];
  const float* Wq    = (const float*)d_in[1];
  const float* Wk    = (const float*)d_in[2];
  const float* Wv    = (const float*)d_in[3];
  const float* Wproj = (const float*)d_in[4];
  const float* a_raw = (const float*)d_in[5];
  const float* b_raw = (const float*)d_in[6];
  const float* state = (const float*)d_in[7];

  char* ws = (char*)d_ws;
  unsigned short* xbf = (unsigned short*)ws;                    // 16MB; reused as y after QKV GEMM
  unsigned short* W3  = (unsigned short*)(ws + (16l << 20));    // 6MB  [Wq;Wk;Wv]
  unsigned short* Wp  = (unsigned short*)(ws + (22l << 20));    // 2MB
  unsigned short* qkv = (unsigned short*)(ws + (24l << 20));    // 48MB
  float* out = (float*)d_out;
  float* state_out = out + (long)B_ * T_ * C_;

  cvt_kernel<<<dim3(8192), dim3(256), 0, stream>>>(x, xbf, 8388608);
  cvt_kernel<<<dim3(1024), dim3(256), 0, stream>>>(Wq, W3, 1048576);
  cvt_kernel<<<dim3(1024), dim3(256), 0, stream>>>(Wk, W3 + 1048576, 1048576);
  cvt_kernel<<<dim3(1024), dim3(256), 0, stream>>>(Wv, W3 + 2097152, 1048576);
  cvt_kernel<<<dim3(1024), dim3(256), 0, stream>>>(Wproj, Wp, 1048576);

  gemm_bt<1><<<dim3(3072 / 128, 8192 / 128), dim3(256), 0, stream>>>(xbf, W3, (void*)qkv, 8192, 3072, 1024);

  scan_kernel<<<dim3(256), dim3(256), 0, stream>>>(qkv, a_raw, b_raw, state, xbf, state_out);

  gemm_bt<0><<<dim3(1024 / 128, 8192 / 128), dim3(256), 0, stream>>>(xbf, Wp, (void*)out, 8192, 1024, 1024);
}

// Round 3
// 218.358 us; speedup vs baseline: 3.9911x; 3.9911x over previous
//
#include <hip/hip_runtime.h>
#include <hip/hip_bf16.h>
#include <cstdint>

#define B_ 4
#define T_ 2048
#define C_ 1024
#define H_ 16
#define D_ 64
#define NC_ 32   // chunks
#define L_ 64    // chunk length

typedef __attribute__((ext_vector_type(8))) short bf16x8;
typedef __attribute__((ext_vector_type(4))) float f32x4;

static __device__ __forceinline__ unsigned short f2bf(float f) {
  unsigned u = __float_as_uint(f);
  u += 0x7fff + ((u >> 16) & 1);   // round-to-nearest-even
  return (unsigned short)(u >> 16);
}
static __device__ __forceinline__ float bf2f(unsigned short b) {
  return __uint_as_float(((unsigned)b) << 16);
}
// XOR swizzle for 128B-stride LDS rows (T2): keeps 16B alignment, <=2-way conflicts
static __device__ __forceinline__ int swz128(int row, int byte) {
  return row * 128 + (byte ^ ((row & 7) << 4));
}

// ---------------- f32 -> bf16 convert ----------------
__global__ __launch_bounds__(256) void cvt_kernel(const float* __restrict__ src,
                                                  unsigned short* __restrict__ dst, int n) {
  int i = (blockIdx.x * 256 + threadIdx.x) * 4;
  if (i >= n) return;
  float4 v = *reinterpret_cast<const float4*>(src + i);
  ushort4 o;
  o.x = f2bf(v.x); o.y = f2bf(v.y); o.z = f2bf(v.z); o.w = f2bf(v.w);
  *reinterpret_cast<ushort4*>(dst + i) = o;
}

// ---------------- bf16 GEMM: C[M,N] = A[M,K] * B[N,K]^T ----------------
template<int OUT_BF16>
__global__ __launch_bounds__(256) void gemm_bt(const unsigned short* __restrict__ A,
                                               const unsigned short* __restrict__ Bw,
                                               void* __restrict__ Cp,
                                               int M, int N, int K) {
  __shared__ __align__(16) unsigned short sA[128 * 32];
  __shared__ __align__(16) unsigned short sB[128 * 32];
  const int tid = threadIdx.x;
  const int wid = tid >> 6, lane = tid & 63;
  const int wm = wid >> 1, wn = wid & 1;
  const long blockM = (long)blockIdx.y * 128;
  const long blockN = (long)blockIdx.x * 128;

  f32x4 acc[4][4] = {};

  const int ar = lane >> 2;
  const int ac = (lane & 3) * 8;
  const unsigned short* Abase = A + (blockM + wid * 32 + ar) * (long)K + ac;
  const unsigned short* Bbase = Bw + (blockN + wid * 32 + ar) * (long)K + ac;
  char* sAb = (char*)sA + wid * 2048;
  char* sBb = (char*)sB + wid * 2048;

  for (int k0 = 0; k0 < K; k0 += 32) {
    __syncthreads();
    __builtin_amdgcn_global_load_lds((const __attribute__((address_space(1))) void*)(Abase + k0),
                                     (__attribute__((address_space(3))) void*)(sAb), 16, 0, 0);
    __builtin_amdgcn_global_load_lds((const __attribute__((address_space(1))) void*)(Abase + 16 * (long)K + k0),
                                     (__attribute__((address_space(3))) void*)(sAb + 1024), 16, 0, 0);
    __builtin_amdgcn_global_load_lds((const __attribute__((address_space(1))) void*)(Bbase + k0),
                                     (__attribute__((address_space(3))) void*)(sBb), 16, 0, 0);
    __builtin_amdgcn_global_load_lds((const __attribute__((address_space(1))) void*)(Bbase + 16 * (long)K + k0),
                                     (__attribute__((address_space(3))) void*)(sBb + 1024), 16, 0, 0);
    __syncthreads();

    const int koff = (lane >> 4) * 8;
    const int rA = wm * 64 + (lane & 15);
    const int rB = wn * 64 + (lane & 15);
    bf16x8 af[4], bfr[4];
#pragma unroll
    for (int m = 0; m < 4; ++m)
      af[m] = *reinterpret_cast<const bf16x8*>(&sA[(rA + m * 16) * 32 + koff]);
#pragma unroll
    for (int n = 0; n < 4; ++n)
      bfr[n] = *reinterpret_cast<const bf16x8*>(&sB[(rB + n * 16) * 32 + koff]);
#pragma unroll
    for (int m = 0; m < 4; ++m)
#pragma unroll
      for (int n = 0; n < 4; ++n)
        acc[m][n] = __builtin_amdgcn_mfma_f32_16x16x32_bf16(af[m], bfr[n], acc[m][n], 0, 0, 0);
  }

  const int cr = (lane >> 4) * 4;
  const int cc = lane & 15;
#pragma unroll
  for (int m = 0; m < 4; ++m) {
    long R = blockM + wm * 64 + m * 16 + cr;
#pragma unroll
    for (int n = 0; n < 4; ++n) {
      long Cc = blockN + wn * 64 + n * 16 + cc;
#pragma unroll
      for (int r = 0; r < 4; ++r) {
        if (OUT_BF16)
          ((unsigned short*)Cp)[(R + r) * (long)N + Cc] = f2bf(acc[m][n][r]);
        else
          ((float*)Cp)[(R + r) * (long)N + Cc] = acc[m][n][r];
      }
    }
  }
}

// ---------------- phase 1: per (bh, chunk) WY precompute ----------------
// normalizes k in place (qkv k-slot), computes SL = stril(Q K^T),
// solves (I + a*stril(A)) U = b*V  and  (I + a*stril(A)) W = a*K  (fwd subst)
__global__ __launch_bounds__(256) void chunk_prep(
    unsigned short* __restrict__ qkv,
    const float* __restrict__ a_raw, const float* __restrict__ b_raw,
    unsigned short* __restrict__ Ubuf, unsigned short* __restrict__ Wbuf,
    unsigned short* __restrict__ SLbuf) {
  __shared__ __align__(16) unsigned short sK[64 * 64];  // swizzled [t][e]
  __shared__ __align__(16) unsigned short sQ[64 * 64];  // swizzled [t][e]
  __shared__ __align__(16) unsigned short sV[64 * 64];  // linear   [t][e]
  __shared__ float sA[64 * 64];                         // linear   [t][j]

  const int blk = blockIdx.x;           // bh*32 + c
  const int bh = blk >> 5, c = blk & 31;
  const int b = bh >> 4, h = bh & 15;
  const int tid = threadIdx.x;
  const int wid = tid >> 6, lane = tid & 63;

  const float alpha = 0.5f / (1.f + __expf(-a_raw[h]));
  const float beta  = 0.5f / (1.f + __expf(-b_raw[h]));

  {
    const int row = tid >> 2, cg = tid & 3;
    unsigned short* gp = qkv + (long)(b * 2048 + c * 64 + row) * 3072 + h * 64 + cg * 16;
    bf16x8 q0 = *(const bf16x8*)(gp);
    bf16x8 q1 = *(const bf16x8*)(gp + 8);
    bf16x8 k0 = *(const bf16x8*)(gp + 1024);
    bf16x8 k1 = *(const bf16x8*)(gp + 1024 + 8);
    bf16x8 v0 = *(const bf16x8*)(gp + 2048);
    bf16x8 v1 = *(const bf16x8*)(gp + 2048 + 8);
    float kf[16];
    float ss = 0.f;
#pragma unroll
    for (int i = 0; i < 8; ++i) { kf[i] = bf2f((unsigned short)k0[i]); ss += kf[i] * kf[i]; }
#pragma unroll
    for (int i = 0; i < 8; ++i) { kf[8 + i] = bf2f((unsigned short)k1[i]); ss += kf[8 + i] * kf[8 + i]; }
    ss += __shfl_xor(ss, 1);
    ss += __shfl_xor(ss, 2);
    const float inv = 1.f / fmaxf(sqrtf(ss), 1e-12f);
    bf16x8 n0, n1;
#pragma unroll
    for (int i = 0; i < 8; ++i) { n0[i] = (short)f2bf(kf[i] * inv); n1[i] = (short)f2bf(kf[8 + i] * inv); }
    *(bf16x8*)((char*)sK + swz128(row, cg * 32)) = n0;
    *(bf16x8*)((char*)sK + swz128(row, cg * 32 + 16)) = n1;
    *(bf16x8*)(gp + 1024) = n0;          // write normalized k back for phase 2
    *(bf16x8*)(gp + 1024 + 8) = n1;
    *(bf16x8*)((char*)sQ + swz128(row, cg * 32)) = q0;
    *(bf16x8*)((char*)sQ + swz128(row, cg * 32 + 16)) = q1;
    *(bf16x8*)((char*)sV + row * 128 + cg * 32) = v0;
    *(bf16x8*)((char*)sV + row * 128 + cg * 32 + 16) = v1;
  }
  __syncthreads();

  const int rfrag = lane & 15, koff = (lane >> 4) * 8, crow = (lane >> 4) * 4;
  const int w2 = wid & 1;
  if (wid < 2) {
    // A = K K^T (f32 to LDS)
#pragma unroll
    for (int mt = 0; mt < 2; ++mt) {
      const int m = w2 * 2 + mt;
      const int ra = 16 * m + rfrag;
      f32x4 acc[4] = {};
#pragma unroll
      for (int ks = 0; ks < 2; ++ks) {
        bf16x8 af = *(const bf16x8*)((const char*)sK + swz128(ra, ks * 64 + koff * 2));
#pragma unroll
        for (int n = 0; n < 4; ++n) {
          bf16x8 bf = *(const bf16x8*)((const char*)sK + swz128(16 * n + rfrag, ks * 64 + koff * 2));
          acc[n] = __builtin_amdgcn_mfma_f32_16x16x32_bf16(af, bf, acc[n], 0, 0, 0);
        }
      }
#pragma unroll
      for (int n = 0; n < 4; ++n)
#pragma unroll
        for (int r = 0; r < 4; ++r)
          sA[(16 * m + crow + r) * 64 + 16 * n + rfrag] = acc[n][r];
    }
  } else {
    // SL = stril(Q K^T) -> global bf16
#pragma unroll
    for (int mt = 0; mt < 2; ++mt) {
      const int m = w2 * 2 + mt;
      const int ra = 16 * m + rfrag;
      f32x4 acc[4] = {};
#pragma unroll
      for (int ks = 0; ks < 2; ++ks) {
        bf16x8 af = *(const bf16x8*)((const char*)sQ + swz128(ra, ks * 64 + koff * 2));
#pragma unroll
        for (int n = 0; n < 4; ++n) {
          bf16x8 bf = *(const bf16x8*)((const char*)sK + swz128(16 * n + rfrag, ks * 64 + koff * 2));
          acc[n] = __builtin_amdgcn_mfma_f32_16x16x32_bf16(af, bf, acc[n], 0, 0, 0);
        }
      }
#pragma unroll
      for (int n = 0; n < 4; ++n)
#pragma unroll
        for (int r = 0; r < 4; ++r) {
          int t = 16 * m + crow + r, j = 16 * n + rfrag;
          SLbuf[(long)blk * 4096 + t * 64 + j] = (j < t) ? f2bf(acc[n][r]) : (unsigned short)0;
        }
    }
  }
  __syncthreads();

  // forward substitution: x_t = rhs_t - alpha * sum_{j<t} A[t][j] x_j
  if (wid < 2) {
    const int d = lane;
    float x[64];
#pragma unroll
    for (int t = 0; t < 64; ++t) {
      float rhs;
      if (wid == 0) rhs = beta * bf2f(sV[t * 64 + d]);
      else          rhs = alpha * bf2f(*(const unsigned short*)((const char*)sK + swz128(t, 2 * d)));
      float s = 0.f;
#pragma unroll
      for (int j = 0; j < t; ++j) s = fmaf(sA[t * 64 + j], x[j], s);
      x[t] = rhs - alpha * s;
    }
    unsigned short* ob = (wid == 0 ? Ubuf : Wbuf) + (long)blk * 4096 + d;
#pragma unroll
    for (int t = 0; t < 64; ++t) ob[t * 64] = f2bf(x[t]);
  }
}

// ---------------- phase 2: sequential chunk recurrence (pure MFMA) ----------------
// per chunk: G = U - W*S^T ; Y = Q*S^T + SL*G ; S += G^T * K
__global__ __launch_bounds__(256) void chunk_scan(
    const unsigned short* __restrict__ qkv,
    const unsigned short* __restrict__ Ubuf, const unsigned short* __restrict__ Wbuf,
    const unsigned short* __restrict__ SLbuf,
    const float* __restrict__ state_in, unsigned short* __restrict__ ybuf,
    float* __restrict__ state_out) {
  __shared__ __align__(16) unsigned short sQ[64 * 64];   // [t][e] swz
  __shared__ __align__(16) unsigned short sW[64 * 64];   // [t][e] swz
  __shared__ __align__(16) unsigned short sSL[64 * 64];  // [t][j] swz
  __shared__ __align__(16) unsigned short sKT[64 * 64];  // [e][t] swz (K transposed)
  __shared__ __align__(16) unsigned short sU[64 * 32];   // [t][dl] linear (this d-half)
  __shared__ __align__(16) unsigned short sGT[32 * 64];  // [dl][t] swz
  __shared__ __align__(16) unsigned short sS[32 * 64];   // [dl][e] swz (bf16 state)

  const int blk = blockIdx.x;          // bh*2 + dh
  const int bh = blk >> 1, dh = blk & 1;
  const int b = bh >> 4, h = bh & 15;
  const int tid = threadIdx.x, wid = tid >> 6, lane = tid & 63;
  const int rfrag = lane & 15, koff = (lane >> 4) * 8, crow = (lane >> 4) * 4;

  // persistent S accumulator: wave (wid): m-tile = wid&1 (d-local), n-tiles = (wid>>1)*2+{0,1} (e)
  const int mS = wid & 1, nS0 = (wid >> 1) * 2;
  f32x4 sacc[2];
#pragma unroll
  for (int nn = 0; nn < 2; ++nn)
#pragma unroll
    for (int r = 0; r < 4; ++r)
      sacc[nn][r] = state_in[(long)bh * 4096 + (dh * 32 + 16 * mS + crow + r) * 64 + 16 * (nS0 + nn) + rfrag];
#pragma unroll
  for (int nn = 0; nn < 2; ++nn)
#pragma unroll
    for (int r = 0; r < 4; ++r) {
      int dr = 16 * mS + crow + r, e = 16 * (nS0 + nn) + rfrag;
      *(unsigned short*)((char*)sS + swz128(dr, 2 * e)) = f2bf(sacc[nn][r]);
    }

  for (int c = 0; c < NC_; ++c) {
    {  // tile loads
      const int row = tid >> 2, cg = tid & 3;
      const unsigned short* gp = qkv + (long)(b * 2048 + c * 64 + row) * 3072 + h * 64 + cg * 16;
      bf16x8 qv0 = *(const bf16x8*)gp;
      bf16x8 qv1 = *(const bf16x8*)(gp + 8);
      bf16x8 kv0 = *(const bf16x8*)(gp + 1024);
      bf16x8 kv1 = *(const bf16x8*)(gp + 1024 + 8);
      const long tb = ((long)(bh * 32 + c) * 64 + row) * 64 + cg * 16;
      bf16x8 wv0 = *(const bf16x8*)(Wbuf + tb);
      bf16x8 wv1 = *(const bf16x8*)(Wbuf + tb + 8);
      bf16x8 sl0 = *(const bf16x8*)(SLbuf + tb);
      bf16x8 sl1 = *(const bf16x8*)(SLbuf + tb + 8);
      *(bf16x8*)((char*)sQ + swz128(row, cg * 32)) = qv0;
      *(bf16x8*)((char*)sQ + swz128(row, cg * 32 + 16)) = qv1;
      *(bf16x8*)((char*)sW + swz128(row, cg * 32)) = wv0;
      *(bf16x8*)((char*)sW + swz128(row, cg * 32 + 16)) = wv1;
      *(bf16x8*)((char*)sSL + swz128(row, cg * 32)) = sl0;
      *(bf16x8*)((char*)sSL + swz128(row, cg * 32 + 16)) = sl1;
#pragma unroll
      for (int i = 0; i < 8; ++i) {
        *(unsigned short*)((char*)sKT + swz128(cg * 16 + i, 2 * row)) = (unsigned short)kv0[i];
        *(unsigned short*)((char*)sKT + swz128(cg * 16 + 8 + i, 2 * row)) = (unsigned short)kv1[i];
      }
      // U tile: 64 rows x 32 el (this d-half) = 256 x bf16x8 -> all 256 threads
      {
        int ur = tid >> 2, uq = tid & 3;
        bf16x8 uv = *(const bf16x8*)(Ubuf + ((long)(bh * 32 + c) * 64 + ur) * 64 + dh * 32 + uq * 8);
        *(bf16x8*)((char*)sU + (ur * 32 + uq * 8) * 2) = uv;
      }
    }
    __syncthreads();

    // stage A: P1 = W*S^T (wave m-tile = wid over t), Yacc = Q*S^T
    const int ta = 16 * wid + rfrag;
    f32x4 p[2] = {};
    f32x4 yac[2] = {};
#pragma unroll
    for (int ks = 0; ks < 2; ++ks) {
      bf16x8 afw = *(const bf16x8*)((const char*)sW + swz128(ta, ks * 64 + koff * 2));
      bf16x8 afq = *(const bf16x8*)((const char*)sQ + swz128(ta, ks * 64 + koff * 2));
#pragma unroll
      for (int n = 0; n < 2; ++n) {
        bf16x8 bf = *(const bf16x8*)((const char*)sS + swz128(16 * n + rfrag, ks * 64 + koff * 2));
        p[n] = __builtin_amdgcn_mfma_f32_16x16x32_bf16(afw, bf, p[n], 0, 0, 0);
        yac[n] = __builtin_amdgcn_mfma_f32_16x16x32_bf16(afq, bf, yac[n], 0, 0, 0);
      }
    }
    // G = U - P1 -> GT (transposed, bf16)
#pragma unroll
    for (int n = 0; n < 2; ++n)
#pragma unroll
      for (int r = 0; r < 4; ++r) {
        int t = 16 * wid + crow + r, dl = 16 * n + rfrag;
        float g = bf2f(sU[t * 32 + dl]) - p[n][r];
        *(unsigned short*)((char*)sGT + swz128(dl, 2 * t)) = f2bf(g);
      }
    __syncthreads();

    // stage B: Y += SL*G ; S += G^T*K
#pragma unroll
    for (int ks = 0; ks < 2; ++ks) {
      bf16x8 af = *(const bf16x8*)((const char*)sSL + swz128(ta, ks * 64 + koff * 2));
#pragma unroll
      for (int n = 0; n < 2; ++n) {
        bf16x8 bf = *(const bf16x8*)((const char*)sGT + swz128(16 * n + rfrag, ks * 64 + koff * 2));
        yac[n] = __builtin_amdgcn_mfma_f32_16x16x32_bf16(af, bf, yac[n], 0, 0, 0);
      }
    }
#pragma unroll
    for (int n = 0; n < 2; ++n)
#pragma unroll
      for (int r = 0; r < 4; ++r) {
        int t = 16 * wid + crow + r;
        ybuf[(long)(b * 2048 + c * 64 + t) * 1024 + h * 64 + dh * 32 + 16 * n + rfrag] = f2bf(yac[n][r]);
      }
#pragma unroll
    for (int ks = 0; ks < 2; ++ks) {
      bf16x8 af = *(const bf16x8*)((const char*)sGT + swz128(16 * mS + rfrag, ks * 64 + koff * 2));
#pragma unroll
      for (int nn = 0; nn < 2; ++nn) {
        bf16x8 bf = *(const bf16x8*)((const char*)sKT + swz128(16 * (nS0 + nn) + rfrag, ks * 64 + koff * 2));
        sacc[nn] = __builtin_amdgcn_mfma_f32_16x16x32_bf16(af, bf, sacc[nn], 0, 0, 0);
      }
    }
    __syncthreads();
    // refresh bf16 state tile
#pragma unroll
    for (int nn = 0; nn < 2; ++nn)
#pragma unroll
      for (int r = 0; r < 4; ++r) {
        int dr = 16 * mS + crow + r, e = 16 * (nS0 + nn) + rfrag;
        *(unsigned short*)((char*)sS + swz128(dr, 2 * e)) = f2bf(sacc[nn][r]);
      }
  }

#pragma unroll
  for (int nn = 0; nn < 2; ++nn)
#pragma unroll
    for (int r = 0; r < 4; ++r)
      state_out[(long)bh * 4096 + (dh * 32 + 16 * mS + crow + r) * 64 + 16 * (nS0 + nn) + rfrag] = sacc[nn][r];
}

// ---------------- fallback sequential scan (if ws too small) ----------------
__global__ __launch_bounds__(256) void scan_kernel(const unsigned short* __restrict__ qkv,
                                                   const float* __restrict__ alpha_raw,
                                                   const float* __restrict__ beta_raw,
                                                   const float* __restrict__ state_in,
                                                   unsigned short* __restrict__ y,
                                                   float* __restrict__ state_out) {
  const int blk = blockIdx.x;
  const int bh = blk >> 2, rg = blk & 3;
  const int b = bh >> 4, h = bh & 15;
  const int tid = threadIdx.x;
  const int lr = tid >> 4, cg = tid & 15;
  const int row = rg * 16 + lr;
  const int c0 = cg * 4;

  float s0, s1, s2, s3;
  {
    float4 si = *reinterpret_cast<const float4*>(state_in + ((long)bh * D_ + row) * D_ + c0);
    s0 = si.x; s1 = si.y; s2 = si.z; s3 = si.w;
  }
  const float alpha = 0.5f / (1.f + __expf(-alpha_raw[h]));
  const float beta  = 0.5f / (1.f + __expf(-beta_raw[h]));

  const unsigned short* qp = qkv + (long)b * T_ * 3072 + h * 64 + c0;
  const unsigned short* kp = qp + 1024;
  const unsigned short* vp = qkv + (long)b * T_ * 3072 + 2048 + h * 64 + row;
  unsigned short* yp = y + (long)b * T_ * 1024 + h * 64 + row;

  ushort4 q4 = *(const ushort4*)qp;
  ushort4 k4 = *(const ushort4*)kp;
  unsigned short vs = *vp;

  for (int t = 0; t < T_; ++t) {
    ushort4 q4n = {}, k4n = {}; unsigned short vsn = 0;
    if (t + 1 < T_) {
      q4n = *(const ushort4*)(qp + (long)(t + 1) * 3072);
      k4n = *(const ushort4*)(kp + (long)(t + 1) * 3072);
      vsn = *(vp + (long)(t + 1) * 3072);
    }
    float q0 = bf2f(q4.x), q1 = bf2f(q4.y), q2 = bf2f(q4.z), q3 = bf2f(q4.w);
    float k0 = bf2f(k4.x), k1 = bf2f(k4.y), k2 = bf2f(k4.z), k3 = bf2f(k4.w);
    float vf = bf2f(vs);
    float py = s0 * q0 + s1 * q1 + s2 * q2 + s3 * q3;
    float pk = s0 * k0 + s1 * k1 + s2 * k2 + s3 * k3;
    float ps = k0 * k0 + k1 * k1 + k2 * k2 + k3 * k3;
#pragma unroll
    for (int m = 1; m < 16; m <<= 1) {
      py += __shfl_xor(py, m);
      pk += __shfl_xor(pk, m);
      ps += __shfl_xor(ps, m);
    }
    float inv = 1.f / fmaxf(sqrtf(ps), 1e-12f);
    if (cg == 0) yp[(long)t * 1024] = f2bf(py);
    float coef = (beta * vf - alpha * pk * inv) * inv;
    s0 = fmaf(coef, k0, s0);
    s1 = fmaf(coef, k1, s1);
    s2 = fmaf(coef, k2, s2);
    s3 = fmaf(coef, k3, s3);
    q4 = q4n; k4 = k4n; vs = vsn;
  }
  float4 so; so.x = s0; so.y = s1; so.z = s2; so.w = s3;
  *reinterpret_cast<float4*>(state_out + ((long)bh * D_ + row) * D_ + c0) = so;
}

// ---------------- launch ----------------
extern "C" void kernel_launch(void* const* d_in, const int* in_sizes, int n_in,
                              void* d_out, int out_size, void* d_ws, size_t ws_size,
                              hipStream_t stream) {
  (void)in_sizes; (void)n_in; (void)out_size;
  const float* x     = (const float*)d_in[0];
  const float* Wq    = (const float*)d_in[1];
  const float* Wk    = (const float*)d_in[2];
  const float* Wv    = (const float*)d_in[3];
  const float* Wproj = (const float*)d_in[4];
  const float* a_raw = (const float*)d_in[5];
  const float* b_raw = (const float*)d_in[6];
  const float* state = (const float*)d_in[7];

  char* ws = (char*)d_ws;
  unsigned short* xbf = (unsigned short*)ws;                    // 16MB; reused as y
  unsigned short* W3  = (unsigned short*)(ws + (16l << 20));    // 6MB [Wq;Wk;Wv]
  unsigned short* Wp  = (unsigned short*)(ws + (22l << 20));    // 2MB
  unsigned short* qkv = (unsigned short*)(ws + (24l << 20));    // 48MB
  unsigned short* Ub  = (unsigned short*)(ws + (72l << 20));    // 16MB
  unsigned short* Wb  = (unsigned short*)(ws + (88l << 20));    // 16MB
  unsigned short* SLb = (unsigned short*)(ws + (104l << 20));   // 16MB -> 120MB total
  float* out = (float*)d_out;
  float* state_out = out + (long)B_ * T_ * C_;

  cvt_kernel<<<dim3(8192), dim3(256), 0, stream>>>(x, xbf, 8388608);
  cvt_kernel<<<dim3(1024), dim3(256), 0, stream>>>(Wq, W3, 1048576);
  cvt_kernel<<<dim3(1024), dim3(256), 0, stream>>>(Wk, W3 + 1048576, 1048576);
  cvt_kernel<<<dim3(1024), dim3(256), 0, stream>>>(Wv, W3 + 2097152, 1048576);
  cvt_kernel<<<dim3(1024), dim3(256), 0, stream>>>(Wproj, Wp, 1048576);

  gemm_bt<1><<<dim3(3072 / 128, 8192 / 128), dim3(256), 0, stream>>>(xbf, W3, (void*)qkv, 8192, 3072, 1024);

  if (ws_size >= (121ul << 20)) {
    chunk_prep<<<dim3(2048), dim3(256), 0, stream>>>(qkv, a_raw, b_raw, Ub, Wb, SLb);
    chunk_scan<<<dim3(128), dim3(256), 0, stream>>>(qkv, Ub, Wb, SLb, state, xbf, state_out);
  } else {
    scan_kernel<<<dim3(256), dim3(256), 0, stream>>>(qkv, a_raw, b_raw, state, xbf, state_out);
  }

  gemm_bt<0><<<dim3(1024 / 128, 8192 / 128), dim3(256), 0, stream>>>(xbf, Wp, (void*)out, 8192, 1024, 1024);
}

// Round 4
// 216.238 us; speedup vs baseline: 4.0302x; 1.0098x over previous
//
#include <hip/hip_runtime.h>
#include <hip/hip_bf16.h>
#include <cstdint>

#define B_ 4
#define T_ 2048
#define C_ 1024
#define H_ 16
#define D_ 64
#define NC_ 32   // chunks
#define L_ 64    // chunk length

typedef __attribute__((ext_vector_type(8))) short bf16x8;
typedef __attribute__((ext_vector_type(4))) float f32x4;

static __device__ __forceinline__ unsigned short f2bf(float f) {
  unsigned u = __float_as_uint(f);
  u += 0x7fff + ((u >> 16) & 1);   // round-to-nearest-even
  return (unsigned short)(u >> 16);
}
static __device__ __forceinline__ float bf2f(unsigned short b) {
  return __uint_as_float(((unsigned)b) << 16);
}
// XOR swizzle for 128B-stride LDS rows (T2): keeps 16B alignment, <=2-way conflicts
static __device__ __forceinline__ int swz128(int row, int byte) {
  return row * 128 + (byte ^ ((row & 7) << 4));
}

// ---------------- f32 -> bf16 convert ----------------
__global__ __launch_bounds__(256) void cvt_kernel(const float* __restrict__ src,
                                                  unsigned short* __restrict__ dst, int n) {
  int i = (blockIdx.x * 256 + threadIdx.x) * 4;
  if (i >= n) return;
  float4 v = *reinterpret_cast<const float4*>(src + i);
  ushort4 o;
  o.x = f2bf(v.x); o.y = f2bf(v.y); o.z = f2bf(v.z); o.w = f2bf(v.w);
  *reinterpret_cast<ushort4*>(dst + i) = o;
}

// ---------------- bf16 GEMM: C[M,N] = A[M,K] * B[N,K]^T ----------------
template<int OUT_BF16>
__global__ __launch_bounds__(256) void gemm_bt(const unsigned short* __restrict__ A,
                                               const unsigned short* __restrict__ Bw,
                                               void* __restrict__ Cp,
                                               int M, int N, int K) {
  __shared__ __align__(16) unsigned short sA[128 * 32];
  __shared__ __align__(16) unsigned short sB[128 * 32];
  const int tid = threadIdx.x;
  const int wid = tid >> 6, lane = tid & 63;
  const int wm = wid >> 1, wn = wid & 1;
  const long blockM = (long)blockIdx.y * 128;
  const long blockN = (long)blockIdx.x * 128;

  f32x4 acc[4][4] = {};

  const int ar = lane >> 2;
  const int ac = (lane & 3) * 8;
  const unsigned short* Abase = A + (blockM + wid * 32 + ar) * (long)K + ac;
  const unsigned short* Bbase = Bw + (blockN + wid * 32 + ar) * (long)K + ac;
  char* sAb = (char*)sA + wid * 2048;
  char* sBb = (char*)sB + wid * 2048;

  for (int k0 = 0; k0 < K; k0 += 32) {
    __syncthreads();
    __builtin_amdgcn_global_load_lds((const __attribute__((address_space(1))) void*)(Abase + k0),
                                     (__attribute__((address_space(3))) void*)(sAb), 16, 0, 0);
    __builtin_amdgcn_global_load_lds((const __attribute__((address_space(1))) void*)(Abase + 16 * (long)K + k0),
                                     (__attribute__((address_space(3))) void*)(sAb + 1024), 16, 0, 0);
    __builtin_amdgcn_global_load_lds((const __attribute__((address_space(1))) void*)(Bbase + k0),
                                     (__attribute__((address_space(3))) void*)(sBb), 16, 0, 0);
    __builtin_amdgcn_global_load_lds((const __attribute__((address_space(1))) void*)(Bbase + 16 * (long)K + k0),
                                     (__attribute__((address_space(3))) void*)(sBb + 1024), 16, 0, 0);
    __syncthreads();

    const int koff = (lane >> 4) * 8;
    const int rA = wm * 64 + (lane & 15);
    const int rB = wn * 64 + (lane & 15);
    bf16x8 af[4], bfr[4];
#pragma unroll
    for (int m = 0; m < 4; ++m)
      af[m] = *reinterpret_cast<const bf16x8*>(&sA[(rA + m * 16) * 32 + koff]);
#pragma unroll
    for (int n = 0; n < 4; ++n)
      bfr[n] = *reinterpret_cast<const bf16x8*>(&sB[(rB + n * 16) * 32 + koff]);
#pragma unroll
    for (int m = 0; m < 4; ++m)
#pragma unroll
      for (int n = 0; n < 4; ++n)
        acc[m][n] = __builtin_amdgcn_mfma_f32_16x16x32_bf16(af[m], bfr[n], acc[m][n], 0, 0, 0);
  }

  const int cr = (lane >> 4) * 4;
  const int cc = lane & 15;
#pragma unroll
  for (int m = 0; m < 4; ++m) {
    long R = blockM + wm * 64 + m * 16 + cr;
#pragma unroll
    for (int n = 0; n < 4; ++n) {
      long Cc = blockN + wn * 64 + n * 16 + cc;
#pragma unroll
      for (int r = 0; r < 4; ++r) {
        if (OUT_BF16)
          ((unsigned short*)Cp)[(R + r) * (long)N + Cc] = f2bf(acc[m][n][r]);
        else
          ((float*)Cp)[(R + r) * (long)N + Cc] = acc[m][n][r];
      }
    }
  }
}

// ---------------- phase 1: per (bh, chunk) WY precompute ----------------
// normalizes k in place (qkv k-slot), computes SL = stril(Q K^T),
// solves (I + a*stril(A)) U = b*V  and  (I + a*stril(A)) W = a*K  (fwd subst)
__global__ __launch_bounds__(256) void chunk_prep(
    unsigned short* __restrict__ qkv,
    const float* __restrict__ a_raw, const float* __restrict__ b_raw,
    unsigned short* __restrict__ Ubuf, unsigned short* __restrict__ Wbuf,
    unsigned short* __restrict__ SLbuf) {
  __shared__ __align__(16) unsigned short sK[64 * 64];  // swizzled [t][e]
  __shared__ __align__(16) unsigned short sQ[64 * 64];  // swizzled [t][e]
  __shared__ __align__(16) unsigned short sV[64 * 64];  // linear   [t][e]
  __shared__ float sA[64 * 64];                         // linear   [t][j]

  const int blk = blockIdx.x;           // bh*32 + c
  const int bh = blk >> 5, c = blk & 31;
  const int b = bh >> 4, h = bh & 15;
  const int tid = threadIdx.x;
  const int wid = tid >> 6, lane = tid & 63;

  const float alpha = 0.5f / (1.f + __expf(-a_raw[h]));
  const float beta  = 0.5f / (1.f + __expf(-b_raw[h]));

  {
    const int row = tid >> 2, cg = tid & 3;
    unsigned short* gp = qkv + (long)(b * 2048 + c * 64 + row) * 3072 + h * 64 + cg * 16;
    bf16x8 q0 = *(const bf16x8*)(gp);
    bf16x8 q1 = *(const bf16x8*)(gp + 8);
    bf16x8 k0 = *(const bf16x8*)(gp + 1024);
    bf16x8 k1 = *(const bf16x8*)(gp + 1024 + 8);
    bf16x8 v0 = *(const bf16x8*)(gp + 2048);
    bf16x8 v1 = *(const bf16x8*)(gp + 2048 + 8);
    float kf[16];
    float ss = 0.f;
#pragma unroll
    for (int i = 0; i < 8; ++i) { kf[i] = bf2f((unsigned short)k0[i]); ss += kf[i] * kf[i]; }
#pragma unroll
    for (int i = 0; i < 8; ++i) { kf[8 + i] = bf2f((unsigned short)k1[i]); ss += kf[8 + i] * kf[8 + i]; }
    ss += __shfl_xor(ss, 1);
    ss += __shfl_xor(ss, 2);
    const float inv = 1.f / fmaxf(sqrtf(ss), 1e-12f);
    bf16x8 n0, n1;
#pragma unroll
    for (int i = 0; i < 8; ++i) { n0[i] = (short)f2bf(kf[i] * inv); n1[i] = (short)f2bf(kf[8 + i] * inv); }
    *(bf16x8*)((char*)sK + swz128(row, cg * 32)) = n0;
    *(bf16x8*)((char*)sK + swz128(row, cg * 32 + 16)) = n1;
    *(bf16x8*)(gp + 1024) = n0;          // write normalized k back for phase 2
    *(bf16x8*)(gp + 1024 + 8) = n1;
    *(bf16x8*)((char*)sQ + swz128(row, cg * 32)) = q0;
    *(bf16x8*)((char*)sQ + swz128(row, cg * 32 + 16)) = q1;
    *(bf16x8*)((char*)sV + row * 128 + cg * 32) = v0;
    *(bf16x8*)((char*)sV + row * 128 + cg * 32 + 16) = v1;
  }
  __syncthreads();

  const int rfrag = lane & 15, koff = (lane >> 4) * 8, crow = (lane >> 4) * 4;
  const int w2 = wid & 1;
  if (wid < 2) {
    // A = K K^T (f32 to LDS)
#pragma unroll
    for (int mt = 0; mt < 2; ++mt) {
      const int m = w2 * 2 + mt;
      const int ra = 16 * m + rfrag;
      f32x4 acc[4] = {};
#pragma unroll
      for (int ks = 0; ks < 2; ++ks) {
        bf16x8 af = *(const bf16x8*)((const char*)sK + swz128(ra, ks * 64 + koff * 2));
#pragma unroll
        for (int n = 0; n < 4; ++n) {
          bf16x8 bf = *(const bf16x8*)((const char*)sK + swz128(16 * n + rfrag, ks * 64 + koff * 2));
          acc[n] = __builtin_amdgcn_mfma_f32_16x16x32_bf16(af, bf, acc[n], 0, 0, 0);
        }
      }
#pragma unroll
      for (int n = 0; n < 4; ++n)
#pragma unroll
        for (int r = 0; r < 4; ++r)
          sA[(16 * m + crow + r) * 64 + 16 * n + rfrag] = acc[n][r];
    }
  } else {
    // SL = stril(Q K^T) -> global bf16
#pragma unroll
    for (int mt = 0; mt < 2; ++mt) {
      const int m = w2 * 2 + mt;
      const int ra = 16 * m + rfrag;
      f32x4 acc[4] = {};
#pragma unroll
      for (int ks = 0; ks < 2; ++ks) {
        bf16x8 af = *(const bf16x8*)((const char*)sQ + swz128(ra, ks * 64 + koff * 2));
#pragma unroll
        for (int n = 0; n < 4; ++n) {
          bf16x8 bf = *(const bf16x8*)((const char*)sK + swz128(16 * n + rfrag, ks * 64 + koff * 2));
          acc[n] = __builtin_amdgcn_mfma_f32_16x16x32_bf16(af, bf, acc[n], 0, 0, 0);
        }
      }
#pragma unroll
      for (int n = 0; n < 4; ++n)
#pragma unroll
        for (int r = 0; r < 4; ++r) {
          int t = 16 * m + crow + r, j = 16 * n + rfrag;
          SLbuf[(long)blk * 4096 + t * 64 + j] = (j < t) ? f2bf(acc[n][r]) : (unsigned short)0;
        }
    }
  }
  __syncthreads();

  // forward substitution: x_t = rhs_t - alpha * sum_{j<t} A[t][j] x_j
  if (wid < 2) {
    const int d = lane;
    float x[64];
#pragma unroll
    for (int t = 0; t < 64; ++t) {
      float rhs;
      if (wid == 0) rhs = beta * bf2f(sV[t * 64 + d]);
      else          rhs = alpha * bf2f(*(const unsigned short*)((const char*)sK + swz128(t, 2 * d)));
      float s = 0.f;
#pragma unroll
      for (int j = 0; j < t; ++j) s = fmaf(sA[t * 64 + j], x[j], s);
      x[t] = rhs - alpha * s;
    }
    unsigned short* ob = (wid == 0 ? Ubuf : Wbuf) + (long)blk * 4096 + d;
#pragma unroll
    for (int t = 0; t < 64; ++t) ob[t * 64] = f2bf(x[t]);
  }
}

// ---------------- phase 2: sequential chunk recurrence (pure MFMA) ----------------
// per chunk: G = U - W*S^T ; Y = Q*S^T + SL*G ; S += G^T * K
// T14: chunk c+1's global loads issued at top of chunk c (reg prefetch);
// "write-at-top -> barrier -> read" keeps single LDS buffer race-free.
__global__ __launch_bounds__(256) void chunk_scan(
    const unsigned short* __restrict__ qkv,
    const unsigned short* __restrict__ Ubuf, const unsigned short* __restrict__ Wbuf,
    const unsigned short* __restrict__ SLbuf,
    const float* __restrict__ state_in, unsigned short* __restrict__ ybuf,
    float* __restrict__ state_out) {
  __shared__ __align__(16) unsigned short sQ[64 * 64];   // [t][e] swz
  __shared__ __align__(16) unsigned short sW[64 * 64];   // [t][e] swz
  __shared__ __align__(16) unsigned short sSL[64 * 64];  // [t][j] swz
  __shared__ __align__(16) unsigned short sKT[64 * 64];  // [e][t] swz (K transposed)
  __shared__ __align__(16) unsigned short sU[64 * 32];   // [t][dl] linear (this d-half)
  __shared__ __align__(16) unsigned short sGT[32 * 64];  // [dl][t] swz
  __shared__ __align__(16) unsigned short sS[32 * 64];   // [dl][e] swz (bf16 state)

  const int blk = blockIdx.x;          // bh*2 + dh
  const int bh = blk >> 1, dh = blk & 1;
  const int b = bh >> 4, h = bh & 15;
  const int tid = threadIdx.x, wid = tid >> 6, lane = tid & 63;
  const int rfrag = lane & 15, koff = (lane >> 4) * 8, crow = (lane >> 4) * 4;
  const int row = tid >> 2, cg = tid & 3;

  // per-thread global bases (chunk 0); per-chunk strides: qkv 64*3072, tiles 64*64
  const unsigned short* gpb = qkv + (long)(b * 2048 + row) * 3072 + h * 64 + cg * 16;
  const long tbb = ((long)(bh * 32) * 64 + row) * 64 + cg * 16;
  const long ubb = ((long)(bh * 32) * 64 + row) * 64 + dh * 32 + cg * 8;

  // prefetch chunk 0 into registers
  bf16x8 qv0, qv1, kv0, kv1, wv0, wv1, sl0, sl1, uv;
  {
    const unsigned short* gp = gpb;
    qv0 = *(const bf16x8*)gp;
    qv1 = *(const bf16x8*)(gp + 8);
    kv0 = *(const bf16x8*)(gp + 1024);
    kv1 = *(const bf16x8*)(gp + 1024 + 8);
    wv0 = *(const bf16x8*)(Wbuf + tbb);
    wv1 = *(const bf16x8*)(Wbuf + tbb + 8);
    sl0 = *(const bf16x8*)(SLbuf + tbb);
    sl1 = *(const bf16x8*)(SLbuf + tbb + 8);
    uv  = *(const bf16x8*)(Ubuf + ubb);
  }

  // persistent S accumulator: wave (wid): m-tile = wid&1 (d-local), n-tiles = (wid>>1)*2+{0,1} (e)
  const int mS = wid & 1, nS0 = (wid >> 1) * 2;
  f32x4 sacc[2];
#pragma unroll
  for (int nn = 0; nn < 2; ++nn)
#pragma unroll
    for (int r = 0; r < 4; ++r)
      sacc[nn][r] = state_in[(long)bh * 4096 + (dh * 32 + 16 * mS + crow + r) * 64 + 16 * (nS0 + nn) + rfrag];
#pragma unroll
  for (int nn = 0; nn < 2; ++nn)
#pragma unroll
    for (int r = 0; r < 4; ++r) {
      int dr = 16 * mS + crow + r, e = 16 * (nS0 + nn) + rfrag;
      *(unsigned short*)((char*)sS + swz128(dr, 2 * e)) = f2bf(sacc[nn][r]);
    }

  for (int c = 0; c < NC_; ++c) {
    // ---- write prefetched tiles to LDS (single buffer; reads of chunk c-1 all
    // completed before the 3rd barrier of iteration c-1) ----
    *(bf16x8*)((char*)sQ + swz128(row, cg * 32)) = qv0;
    *(bf16x8*)((char*)sQ + swz128(row, cg * 32 + 16)) = qv1;
    *(bf16x8*)((char*)sW + swz128(row, cg * 32)) = wv0;
    *(bf16x8*)((char*)sW + swz128(row, cg * 32 + 16)) = wv1;
    *(bf16x8*)((char*)sSL + swz128(row, cg * 32)) = sl0;
    *(bf16x8*)((char*)sSL + swz128(row, cg * 32 + 16)) = sl1;
#pragma unroll
    for (int i = 0; i < 8; ++i) {
      *(unsigned short*)((char*)sKT + swz128(cg * 16 + i, 2 * row)) = (unsigned short)kv0[i];
      *(unsigned short*)((char*)sKT + swz128(cg * 16 + 8 + i, 2 * row)) = (unsigned short)kv1[i];
    }
    *(bf16x8*)((char*)sU + (row * 32 + cg * 8) * 2) = uv;

    // ---- issue next chunk's global loads (latency hides under this chunk) ----
    {
      const int cn = (c + 1 < NC_) ? c + 1 : c;
      const unsigned short* gp = gpb + (long)cn * 64 * 3072;
      const long tb = tbb + (long)cn * 4096;
      qv0 = *(const bf16x8*)gp;
      qv1 = *(const bf16x8*)(gp + 8);
      kv0 = *(const bf16x8*)(gp + 1024);
      kv1 = *(const bf16x8*)(gp + 1024 + 8);
      wv0 = *(const bf16x8*)(Wbuf + tb);
      wv1 = *(const bf16x8*)(Wbuf + tb + 8);
      sl0 = *(const bf16x8*)(SLbuf + tb);
      sl1 = *(const bf16x8*)(SLbuf + tb + 8);
      uv  = *(const bf16x8*)(Ubuf + ubb + (long)cn * 4096);
    }
    __syncthreads();

    // stage A: P1 = W*S^T (wave m-tile = wid over t), Yacc = Q*S^T
    const int ta = 16 * wid + rfrag;
    f32x4 p[2] = {};
    f32x4 yac[2] = {};
#pragma unroll
    for (int ks = 0; ks < 2; ++ks) {
      bf16x8 afw = *(const bf16x8*)((const char*)sW + swz128(ta, ks * 64 + koff * 2));
      bf16x8 afq = *(const bf16x8*)((const char*)sQ + swz128(ta, ks * 64 + koff * 2));
#pragma unroll
      for (int n = 0; n < 2; ++n) {
        bf16x8 bf = *(const bf16x8*)((const char*)sS + swz128(16 * n + rfrag, ks * 64 + koff * 2));
        p[n] = __builtin_amdgcn_mfma_f32_16x16x32_bf16(afw, bf, p[n], 0, 0, 0);
        yac[n] = __builtin_amdgcn_mfma_f32_16x16x32_bf16(afq, bf, yac[n], 0, 0, 0);
      }
    }
    // G = U - P1 -> GT (transposed, bf16)
#pragma unroll
    for (int n = 0; n < 2; ++n)
#pragma unroll
      for (int r = 0; r < 4; ++r) {
        int t = 16 * wid + crow + r, dl = 16 * n + rfrag;
        float g = bf2f(sU[t * 32 + dl]) - p[n][r];
        *(unsigned short*)((char*)sGT + swz128(dl, 2 * t)) = f2bf(g);
      }
    __syncthreads();

    // stage B: Y += SL*G ; S += G^T*K
#pragma unroll
    for (int ks = 0; ks < 2; ++ks) {
      bf16x8 af = *(const bf16x8*)((const char*)sSL + swz128(ta, ks * 64 + koff * 2));
#pragma unroll
      for (int n = 0; n < 2; ++n) {
        bf16x8 bf = *(const bf16x8*)((const char*)sGT + swz128(16 * n + rfrag, ks * 64 + koff * 2));
        yac[n] = __builtin_amdgcn_mfma_f32_16x16x32_bf16(af, bf, yac[n], 0, 0, 0);
      }
    }
#pragma unroll
    for (int n = 0; n < 2; ++n)
#pragma unroll
      for (int r = 0; r < 4; ++r) {
        int t = 16 * wid + crow + r;
        ybuf[(long)(b * 2048 + c * 64 + t) * 1024 + h * 64 + dh * 32 + 16 * n + rfrag] = f2bf(yac[n][r]);
      }
#pragma unroll
    for (int ks = 0; ks < 2; ++ks) {
      bf16x8 af = *(const bf16x8*)((const char*)sGT + swz128(16 * mS + rfrag, ks * 64 + koff * 2));
#pragma unroll
      for (int nn = 0; nn < 2; ++nn) {
        bf16x8 bf = *(const bf16x8*)((const char*)sKT + swz128(16 * (nS0 + nn) + rfrag, ks * 64 + koff * 2));
        sacc[nn] = __builtin_amdgcn_mfma_f32_16x16x32_bf16(af, bf, sacc[nn], 0, 0, 0);
      }
    }
    __syncthreads();
    // refresh bf16 state tile (visible to stage A after the barrier at loop top)
#pragma unroll
    for (int nn = 0; nn < 2; ++nn)
#pragma unroll
      for (int r = 0; r < 4; ++r) {
        int dr = 16 * mS + crow + r, e = 16 * (nS0 + nn) + rfrag;
        *(unsigned short*)((char*)sS + swz128(dr, 2 * e)) = f2bf(sacc[nn][r]);
      }
  }

#pragma unroll
  for (int nn = 0; nn < 2; ++nn)
#pragma unroll
    for (int r = 0; r < 4; ++r)
      state_out[(long)bh * 4096 + (dh * 32 + 16 * mS + crow + r) * 64 + 16 * (nS0 + nn) + rfrag] = sacc[nn][r];
}

// ---------------- launch ----------------
extern "C" void kernel_launch(void* const* d_in, const int* in_sizes, int n_in,
                              void* d_out, int out_size, void* d_ws, size_t ws_size,
                              hipStream_t stream) {
  (void)in_sizes; (void)n_in; (void)out_size; (void)ws_size;
  const float* x     = (const float*)d_in[0];
  const float* Wq    = (const float*)d_in[1];
  const float* Wk    = (const float*)d_in[2];
  const float* Wv    = (const float*)d_in[3];
  const float* Wproj = (const float*)d_in[4];
  const float* a_raw = (const float*)d_in[5];
  const float* b_raw = (const float*)d_in[6];
  const float* state = (const float*)d_in[7];

  char* ws = (char*)d_ws;
  unsigned short* xbf = (unsigned short*)ws;                    // 16MB; reused as y
  unsigned short* W3  = (unsigned short*)(ws + (16l << 20));    // 6MB [Wq;Wk;Wv]
  unsigned short* Wp  = (unsigned short*)(ws + (22l << 20));    // 2MB
  unsigned short* qkv = (unsigned short*)(ws + (24l << 20));    // 48MB
  unsigned short* Ub  = (unsigned short*)(ws + (72l << 20));    // 16MB
  unsigned short* Wb  = (unsigned short*)(ws + (88l << 20));    // 16MB
  unsigned short* SLb = (unsigned short*)(ws + (104l << 20));   // 16MB -> 120MB total
  float* out = (float*)d_out;
  float* state_out = out + (long)B_ * T_ * C_;

  cvt_kernel<<<dim3(8192), dim3(256), 0, stream>>>(x, xbf, 8388608);
  cvt_kernel<<<dim3(1024), dim3(256), 0, stream>>>(Wq, W3, 1048576);
  cvt_kernel<<<dim3(1024), dim3(256), 0, stream>>>(Wk, W3 + 1048576, 1048576);
  cvt_kernel<<<dim3(1024), dim3(256), 0, stream>>>(Wv, W3 + 2097152, 1048576);
  cvt_kernel<<<dim3(1024), dim3(256), 0, stream>>>(Wproj, Wp, 1048576);

  gemm_bt<1><<<dim3(3072 / 128, 8192 / 128), dim3(256), 0, stream>>>(xbf, W3, (void*)qkv, 8192, 3072, 1024);

  chunk_prep<<<dim3(2048), dim3(256), 0, stream>>>(qkv, a_raw, b_raw, Ub, Wb, SLb);
  chunk_scan<<<dim3(128), dim3(256), 0, stream>>>(qkv, Ub, Wb, SLb, state, xbf, state_out);

  gemm_bt<0><<<dim3(1024 / 128, 8192 / 128), dim3(256), 0, stream>>>(xbf, Wp, (void*)out, 8192, 1024, 1024);
}

// Round 5
// 211.814 us; speedup vs baseline: 4.1144x; 1.0209x over previous
//
#include <hip/hip_runtime.h>
#include <hip/hip_bf16.h>
#include <cstdint>

#define B_ 4
#define T_ 2048
#define C_ 1024
#define H_ 16
#define D_ 64
#define NC_ 32   // chunks
#define L_ 64    // chunk length

typedef __attribute__((ext_vector_type(8))) short bf16x8;
typedef __attribute__((ext_vector_type(4))) float f32x4;

static __device__ __forceinline__ unsigned short f2bf(float f) {
  unsigned u = __float_as_uint(f);
  u += 0x7fff + ((u >> 16) & 1);   // round-to-nearest-even
  return (unsigned short)(u >> 16);
}
static __device__ __forceinline__ float bf2f(unsigned short b) {
  return __uint_as_float(((unsigned)b) << 16);
}
// XOR swizzle for 128B-stride LDS rows (T2): keeps 16B alignment, <=2-way conflicts
static __device__ __forceinline__ int swz128(int row, int byte) {
  return row * 128 + (byte ^ ((row & 7) << 4));
}

// ---------------- f32 -> bf16 convert ----------------
__global__ __launch_bounds__(256) void cvt_kernel(const float* __restrict__ src,
                                                  unsigned short* __restrict__ dst, int n) {
  int i = (blockIdx.x * 256 + threadIdx.x) * 4;
  if (i >= n) return;
  float4 v = *reinterpret_cast<const float4*>(src + i);
  ushort4 o;
  o.x = f2bf(v.x); o.y = f2bf(v.y); o.z = f2bf(v.z); o.w = f2bf(v.w);
  *reinterpret_cast<ushort4*>(dst + i) = o;
}

// 4 weight matrices in one launch: blocks [0,1024)->Wq, [1024,2048)->Wk,
// [2048,3072)->Wv (into W3), [3072,4096)->Wproj (into Wp). 1M elems each.
__global__ __launch_bounds__(256) void cvt_w_kernel(const float* __restrict__ wq,
                                                    const float* __restrict__ wk,
                                                    const float* __restrict__ wv,
                                                    const float* __restrict__ wp,
                                                    unsigned short* __restrict__ W3,
                                                    unsigned short* __restrict__ Wp) {
  const int g = blockIdx.x >> 10;
  const float* src = (g == 0) ? wq : (g == 1) ? wk : (g == 2) ? wv : wp;
  unsigned short* dst = (g < 3) ? (W3 + (long)g * 1048576) : Wp;
  int i = ((blockIdx.x & 1023) * 256 + threadIdx.x) * 4;
  float4 v = *reinterpret_cast<const float4*>(src + i);
  ushort4 o;
  o.x = f2bf(v.x); o.y = f2bf(v.y); o.z = f2bf(v.z); o.w = f2bf(v.w);
  *reinterpret_cast<ushort4*>(dst + i) = o;
}

// ---------------- bf16 GEMM: C[M,N] = A[M,K] * B[N,K]^T ----------------
template<int OUT_BF16>
__global__ __launch_bounds__(256) void gemm_bt(const unsigned short* __restrict__ A,
                                               const unsigned short* __restrict__ Bw,
                                               void* __restrict__ Cp,
                                               int M, int N, int K) {
  __shared__ __align__(16) unsigned short sA[128 * 32];
  __shared__ __align__(16) unsigned short sB[128 * 32];
  const int tid = threadIdx.x;
  const int wid = tid >> 6, lane = tid & 63;
  const int wm = wid >> 1, wn = wid & 1;
  const long blockM = (long)blockIdx.y * 128;
  const long blockN = (long)blockIdx.x * 128;

  f32x4 acc[4][4] = {};

  const int ar = lane >> 2;
  const int ac = (lane & 3) * 8;
  const unsigned short* Abase = A + (blockM + wid * 32 + ar) * (long)K + ac;
  const unsigned short* Bbase = Bw + (blockN + wid * 32 + ar) * (long)K + ac;
  char* sAb = (char*)sA + wid * 2048;
  char* sBb = (char*)sB + wid * 2048;

  for (int k0 = 0; k0 < K; k0 += 32) {
    __syncthreads();
    __builtin_amdgcn_global_load_lds((const __attribute__((address_space(1))) void*)(Abase + k0),
                                     (__attribute__((address_space(3))) void*)(sAb), 16, 0, 0);
    __builtin_amdgcn_global_load_lds((const __attribute__((address_space(1))) void*)(Abase + 16 * (long)K + k0),
                                     (__attribute__((address_space(3))) void*)(sAb + 1024), 16, 0, 0);
    __builtin_amdgcn_global_load_lds((const __attribute__((address_space(1))) void*)(Bbase + k0),
                                     (__attribute__((address_space(3))) void*)(sBb), 16, 0, 0);
    __builtin_amdgcn_global_load_lds((const __attribute__((address_space(1))) void*)(Bbase + 16 * (long)K + k0),
                                     (__attribute__((address_space(3))) void*)(sBb + 1024), 16, 0, 0);
    __syncthreads();

    const int koff = (lane >> 4) * 8;
    const int rA = wm * 64 + (lane & 15);
    const int rB = wn * 64 + (lane & 15);
    bf16x8 af[4], bfr[4];
#pragma unroll
    for (int m = 0; m < 4; ++m)
      af[m] = *reinterpret_cast<const bf16x8*>(&sA[(rA + m * 16) * 32 + koff]);
#pragma unroll
    for (int n = 0; n < 4; ++n)
      bfr[n] = *reinterpret_cast<const bf16x8*>(&sB[(rB + n * 16) * 32 + koff]);
#pragma unroll
    for (int m = 0; m < 4; ++m)
#pragma unroll
      for (int n = 0; n < 4; ++n)
        acc[m][n] = __builtin_amdgcn_mfma_f32_16x16x32_bf16(af[m], bfr[n], acc[m][n], 0, 0, 0);
  }

  const int cr = (lane >> 4) * 4;
  const int cc = lane & 15;
#pragma unroll
  for (int m = 0; m < 4; ++m) {
    long R = blockM + wm * 64 + m * 16 + cr;
#pragma unroll
    for (int n = 0; n < 4; ++n) {
      long Cc = blockN + wn * 64 + n * 16 + cc;
#pragma unroll
      for (int r = 0; r < 4; ++r) {
        if (OUT_BF16)
          ((unsigned short*)Cp)[(R + r) * (long)N + Cc] = f2bf(acc[m][n][r]);
        else
          ((float*)Cp)[(R + r) * (long)N + Cc] = acc[m][n][r];
      }
    }
  }
}

// ---------------- phase 1: per (bh, chunk) WY precompute ----------------
// normalizes k in place (qkv k-slot), computes SL = stril(Q K^T),
// solves (I + a*stril(A)) U = b*V  and  (I + a*stril(A)) W = a*K  (fwd subst)
__global__ __launch_bounds__(256) void chunk_prep(
    unsigned short* __restrict__ qkv,
    const float* __restrict__ a_raw, const float* __restrict__ b_raw,
    unsigned short* __restrict__ Ubuf, unsigned short* __restrict__ Wbuf,
    unsigned short* __restrict__ SLbuf) {
  __shared__ __align__(16) unsigned short sK[64 * 64];  // swizzled [t][e]
  __shared__ __align__(16) unsigned short sQ[64 * 64];  // swizzled [t][e]
  __shared__ __align__(16) unsigned short sV[64 * 64];  // linear   [t][e]
  __shared__ float sA[64 * 64];                         // linear   [t][j]

  const int blk = blockIdx.x;           // bh*32 + c
  const int bh = blk >> 5, c = blk & 31;
  const int b = bh >> 4, h = bh & 15;
  const int tid = threadIdx.x;
  const int wid = tid >> 6, lane = tid & 63;

  const float alpha = 0.5f / (1.f + __expf(-a_raw[h]));
  const float beta  = 0.5f / (1.f + __expf(-b_raw[h]));

  {
    const int row = tid >> 2, cg = tid & 3;
    unsigned short* gp = qkv + (long)(b * 2048 + c * 64 + row) * 3072 + h * 64 + cg * 16;
    bf16x8 q0 = *(const bf16x8*)(gp);
    bf16x8 q1 = *(const bf16x8*)(gp + 8);
    bf16x8 k0 = *(const bf16x8*)(gp + 1024);
    bf16x8 k1 = *(const bf16x8*)(gp + 1024 + 8);
    bf16x8 v0 = *(const bf16x8*)(gp + 2048);
    bf16x8 v1 = *(const bf16x8*)(gp + 2048 + 8);
    float kf[16];
    float ss = 0.f;
#pragma unroll
    for (int i = 0; i < 8; ++i) { kf[i] = bf2f((unsigned short)k0[i]); ss += kf[i] * kf[i]; }
#pragma unroll
    for (int i = 0; i < 8; ++i) { kf[8 + i] = bf2f((unsigned short)k1[i]); ss += kf[8 + i] * kf[8 + i]; }
    ss += __shfl_xor(ss, 1);
    ss += __shfl_xor(ss, 2);
    const float inv = 1.f / fmaxf(sqrtf(ss), 1e-12f);
    bf16x8 n0, n1;
#pragma unroll
    for (int i = 0; i < 8; ++i) { n0[i] = (short)f2bf(kf[i] * inv); n1[i] = (short)f2bf(kf[8 + i] * inv); }
    *(bf16x8*)((char*)sK + swz128(row, cg * 32)) = n0;
    *(bf16x8*)((char*)sK + swz128(row, cg * 32 + 16)) = n1;
    *(bf16x8*)(gp + 1024) = n0;          // write normalized k back for phase 2
    *(bf16x8*)(gp + 1024 + 8) = n1;
    *(bf16x8*)((char*)sQ + swz128(row, cg * 32)) = q0;
    *(bf16x8*)((char*)sQ + swz128(row, cg * 32 + 16)) = q1;
    *(bf16x8*)((char*)sV + row * 128 + cg * 32) = v0;
    *(bf16x8*)((char*)sV + row * 128 + cg * 32 + 16) = v1;
  }
  __syncthreads();

  const int rfrag = lane & 15, koff = (lane >> 4) * 8, crow = (lane >> 4) * 4;
  const int w2 = wid & 1;
  if (wid < 2) {
    // A = K K^T (f32 to LDS)
#pragma unroll
    for (int mt = 0; mt < 2; ++mt) {
      const int m = w2 * 2 + mt;
      const int ra = 16 * m + rfrag;
      f32x4 acc[4] = {};
#pragma unroll
      for (int ks = 0; ks < 2; ++ks) {
        bf16x8 af = *(const bf16x8*)((const char*)sK + swz128(ra, ks * 64 + koff * 2));
#pragma unroll
        for (int n = 0; n < 4; ++n) {
          bf16x8 bf = *(const bf16x8*)((const char*)sK + swz128(16 * n + rfrag, ks * 64 + koff * 2));
          acc[n] = __builtin_amdgcn_mfma_f32_16x16x32_bf16(af, bf, acc[n], 0, 0, 0);
        }
      }
#pragma unroll
      for (int n = 0; n < 4; ++n)
#pragma unroll
        for (int r = 0; r < 4; ++r)
          sA[(16 * m + crow + r) * 64 + 16 * n + rfrag] = acc[n][r];
    }
  } else {
    // SL = stril(Q K^T) -> global bf16
#pragma unroll
    for (int mt = 0; mt < 2; ++mt) {
      const int m = w2 * 2 + mt;
      const int ra = 16 * m + rfrag;
      f32x4 acc[4] = {};
#pragma unroll
      for (int ks = 0; ks < 2; ++ks) {
        bf16x8 af = *(const bf16x8*)((const char*)sQ + swz128(ra, ks * 64 + koff * 2));
#pragma unroll
        for (int n = 0; n < 4; ++n) {
          bf16x8 bf = *(const bf16x8*)((const char*)sK + swz128(16 * n + rfrag, ks * 64 + koff * 2));
          acc[n] = __builtin_amdgcn_mfma_f32_16x16x32_bf16(af, bf, acc[n], 0, 0, 0);
        }
      }
#pragma unroll
      for (int n = 0; n < 4; ++n)
#pragma unroll
        for (int r = 0; r < 4; ++r) {
          int t = 16 * m + crow + r, j = 16 * n + rfrag;
          SLbuf[(long)blk * 4096 + t * 64 + j] = (j < t) ? f2bf(acc[n][r]) : (unsigned short)0;
        }
    }
  }
  __syncthreads();

  // forward substitution: x_t = rhs_t - alpha * sum_{j<t} A[t][j] x_j
  if (wid < 2) {
    const int d = lane;
    float x[64];
#pragma unroll
    for (int t = 0; t < 64; ++t) {
      float rhs;
      if (wid == 0) rhs = beta * bf2f(sV[t * 64 + d]);
      else          rhs = alpha * bf2f(*(const unsigned short*)((const char*)sK + swz128(t, 2 * d)));
      float s = 0.f;
#pragma unroll
      for (int j = 0; j < t; ++j) s = fmaf(sA[t * 64 + j], x[j], s);
      x[t] = rhs - alpha * s;
    }
    unsigned short* ob = (wid == 0 ? Ubuf : Wbuf) + (long)blk * 4096 + d;
#pragma unroll
    for (int t = 0; t < 64; ++t) ob[t * 64] = f2bf(x[t]);
  }
}

// ---------------- phase 2: sequential chunk recurrence (pure MFMA) ----------------
// per chunk: G = U - W*S^T ; Y = Q*S^T + SL*G ; S += G^T * K
// Grid: 256 blocks = (b,h) x 4 d-quarters (dl=16) -> every CU busy.
// Per wave (wid = t-tile): 8 MFMA/chunk; S quarter [16][64] persistent in acc.
__global__ __launch_bounds__(256) void chunk_scan(
    const unsigned short* __restrict__ qkv,
    const unsigned short* __restrict__ Ubuf, const unsigned short* __restrict__ Wbuf,
    const unsigned short* __restrict__ SLbuf,
    const float* __restrict__ state_in, unsigned short* __restrict__ ybuf,
    float* __restrict__ state_out) {
  __shared__ __align__(16) unsigned short sQ[64 * 64];   // [t][e] swz
  __shared__ __align__(16) unsigned short sW[64 * 64];   // [t][e] swz
  __shared__ __align__(16) unsigned short sSL[64 * 64];  // [t][j] swz
  __shared__ __align__(16) unsigned short sKT[64 * 64];  // [e][t] swz (K transposed)
  __shared__ __align__(16) unsigned short sU[64 * 16];   // [t][dl] linear (this d-quarter)
  __shared__ __align__(16) unsigned short sGT[16 * 64];  // [dl][t] swz
  __shared__ __align__(16) unsigned short sS[16 * 64];   // [dl][e] swz (bf16 state quarter)

  const int blk = blockIdx.x;          // bh*4 + dq
  const int bh = blk >> 2, dq = blk & 3;
  const int b = bh >> 4, h = bh & 15;
  const int tid = threadIdx.x, wid = tid >> 6, lane = tid & 63;
  const int rfrag = lane & 15, koff = (lane >> 4) * 8, crow = (lane >> 4) * 4;
  const int row = tid >> 2, cg = tid & 3;

  // per-thread global bases (chunk 0); per-chunk strides: qkv 64*3072, tiles 64*64
  const unsigned short* gpb = qkv + (long)(b * 2048 + row) * 3072 + h * 64 + cg * 16;
  const long tbb = ((long)(bh * 32) * 64 + row) * 64 + cg * 16;
  const long ubb = ((long)(bh * 32) * 64 + (tid >> 1)) * 64 + dq * 16 + (tid & 1) * 8;

  // prefetch chunk 0 into registers
  bf16x8 qv0, qv1, kv0, kv1, wv0, wv1, sl0, sl1, uv;
  {
    qv0 = *(const bf16x8*)gpb;
    qv1 = *(const bf16x8*)(gpb + 8);
    kv0 = *(const bf16x8*)(gpb + 1024);
    kv1 = *(const bf16x8*)(gpb + 1024 + 8);
    wv0 = *(const bf16x8*)(Wbuf + tbb);
    wv1 = *(const bf16x8*)(Wbuf + tbb + 8);
    sl0 = *(const bf16x8*)(SLbuf + tbb);
    sl1 = *(const bf16x8*)(SLbuf + tbb + 8);
    uv = (tid < 128) ? *(const bf16x8*)(Ubuf + ubb) : bf16x8{};
  }

  // persistent S quarter: wave wid owns e-cols [16*wid, 16*wid+16)
  f32x4 sacc;
#pragma unroll
  for (int r = 0; r < 4; ++r)
    sacc[r] = state_in[(long)bh * 4096 + (dq * 16 + crow + r) * 64 + 16 * wid + rfrag];
#pragma unroll
  for (int r = 0; r < 4; ++r)
    *(unsigned short*)((char*)sS + swz128(crow + r, 2 * (16 * wid + rfrag))) = f2bf(sacc[r]);

  for (int c = 0; c < NC_; ++c) {
    // ---- write prefetched tiles to LDS (reads of chunk c-1 done before its 3rd barrier) ----
    *(bf16x8*)((char*)sQ + swz128(row, cg * 32)) = qv0;
    *(bf16x8*)((char*)sQ + swz128(row, cg * 32 + 16)) = qv1;
    *(bf16x8*)((char*)sW + swz128(row, cg * 32)) = wv0;
    *(bf16x8*)((char*)sW + swz128(row, cg * 32 + 16)) = wv1;
    *(bf16x8*)((char*)sSL + swz128(row, cg * 32)) = sl0;
    *(bf16x8*)((char*)sSL + swz128(row, cg * 32 + 16)) = sl1;
#pragma unroll
    for (int i = 0; i < 8; ++i) {
      *(unsigned short*)((char*)sKT + swz128(cg * 16 + i, 2 * row)) = (unsigned short)kv0[i];
      *(unsigned short*)((char*)sKT + swz128(cg * 16 + 8 + i, 2 * row)) = (unsigned short)kv1[i];
    }
    if (tid < 128) *(bf16x8*)((char*)sU + ((tid >> 1) * 16 + (tid & 1) * 8) * 2) = uv;

    // ---- issue next chunk's global loads ----
    {
      const int cn = (c + 1 < NC_) ? c + 1 : c;
      const unsigned short* gp = gpb + (long)cn * 64 * 3072;
      const long tb = tbb + (long)cn * 4096;
      qv0 = *(const bf16x8*)gp;
      qv1 = *(const bf16x8*)(gp + 8);
      kv0 = *(const bf16x8*)(gp + 1024);
      kv1 = *(const bf16x8*)(gp + 1024 + 8);
      wv0 = *(const bf16x8*)(Wbuf + tb);
      wv1 = *(const bf16x8*)(Wbuf + tb + 8);
      sl0 = *(const bf16x8*)(SLbuf + tb);
      sl1 = *(const bf16x8*)(SLbuf + tb + 8);
      if (tid < 128) uv = *(const bf16x8*)(Ubuf + ubb + (long)cn * 4096);
    }
    __syncthreads();

    // stage A: P1 = W*S^T, Yacc = Q*S^T  (wave wid = t-tile m; n = dl quarter)
    const int ta = 16 * wid + rfrag;
    f32x4 p = {};
    f32x4 yac = {};
#pragma unroll
    for (int ks = 0; ks < 2; ++ks) {
      bf16x8 afw = *(const bf16x8*)((const char*)sW + swz128(ta, ks * 64 + koff * 2));
      bf16x8 afq = *(const bf16x8*)((const char*)sQ + swz128(ta, ks * 64 + koff * 2));
      bf16x8 bS = *(const bf16x8*)((const char*)sS + swz128(rfrag, ks * 64 + koff * 2));
      p = __builtin_amdgcn_mfma_f32_16x16x32_bf16(afw, bS, p, 0, 0, 0);
      yac = __builtin_amdgcn_mfma_f32_16x16x32_bf16(afq, bS, yac, 0, 0, 0);
    }
    // G = U - P1 -> GT (transposed, bf16)
#pragma unroll
    for (int r = 0; r < 4; ++r) {
      int t = 16 * wid + crow + r;
      float g = bf2f(sU[t * 16 + rfrag]) - p[r];
      *(unsigned short*)((char*)sGT + swz128(rfrag, 2 * t)) = f2bf(g);
    }
    __syncthreads();

    // stage B: Y += SL*G ; S += G^T*K
#pragma unroll
    for (int ks = 0; ks < 2; ++ks) {
      bf16x8 aSL = *(const bf16x8*)((const char*)sSL + swz128(ta, ks * 64 + koff * 2));
      bf16x8 bGT = *(const bf16x8*)((const char*)sGT + swz128(rfrag, ks * 64 + koff * 2));
      yac = __builtin_amdgcn_mfma_f32_16x16x32_bf16(aSL, bGT, yac, 0, 0, 0);
    }
#pragma unroll
    for (int r = 0; r < 4; ++r) {
      int t = 16 * wid + crow + r;
      ybuf[(long)(b * 2048 + c * 64 + t) * 1024 + h * 64 + dq * 16 + rfrag] = f2bf(yac[r]);
    }
#pragma unroll
    for (int ks = 0; ks < 2; ++ks) {
      bf16x8 aGT = *(const bf16x8*)((const char*)sGT + swz128(rfrag, ks * 64 + koff * 2));
      bf16x8 bKT = *(const bf16x8*)((const char*)sKT + swz128(16 * wid + rfrag, ks * 64 + koff * 2));
      sacc = __builtin_amdgcn_mfma_f32_16x16x32_bf16(aGT, bKT, sacc, 0, 0, 0);
    }
    __syncthreads();
    // refresh bf16 state quarter (consumed by stage A after next top barrier)
#pragma unroll
    for (int r = 0; r < 4; ++r)
      *(unsigned short*)((char*)sS + swz128(crow + r, 2 * (16 * wid + rfrag))) = f2bf(sacc[r]);
  }

#pragma unroll
  for (int r = 0; r < 4; ++r)
    state_out[(long)bh * 4096 + (dq * 16 + crow + r) * 64 + 16 * wid + rfrag] = sacc[r];
}

// ---------------- launch ----------------
extern "C" void kernel_launch(void* const* d_in, const int* in_sizes, int n_in,
                              void* d_out, int out_size, void* d_ws, size_t ws_size,
                              hipStream_t stream) {
  (void)in_sizes; (void)n_in; (void)out_size; (void)ws_size;
  const float* x     = (const float*)d_in[0];
  const float* Wq    = (const float*)d_in[1];
  const float* Wk    = (const float*)d_in[2];
  const float* Wv    = (const float*)d_in[3];
  const float* Wproj = (const float*)d_in[4];
  const float* a_raw = (const float*)d_in[5];
  const float* b_raw = (const float*)d_in[6];
  const float* state = (const float*)d_in[7];

  char* ws = (char*)d_ws;
  unsigned short* xbf = (unsigned short*)ws;                    // 16MB; reused as y
  unsigned short* W3  = (unsigned short*)(ws + (16l << 20));    // 6MB [Wq;Wk;Wv]
  unsigned short* Wp  = (unsigned short*)(ws + (22l << 20));    // 2MB
  unsigned short* qkv = (unsigned short*)(ws + (24l << 20));    // 48MB
  unsigned short* Ub  = (unsigned short*)(ws + (72l << 20));    // 16MB
  unsigned short* Wb  = (unsigned short*)(ws + (88l << 20));    // 16MB
  unsigned short* SLb = (unsigned short*)(ws + (104l << 20));   // 16MB -> 120MB total
  float* out = (float*)d_out;
  float* state_out = out + (long)B_ * T_ * C_;

  cvt_kernel<<<dim3(8192), dim3(256), 0, stream>>>(x, xbf, 8388608);
  cvt_w_kernel<<<dim3(4096), dim3(256), 0, stream>>>(Wq, Wk, Wv, Wproj, W3, Wp);

  gemm_bt<1><<<dim3(3072 / 128, 8192 / 128), dim3(256), 0, stream>>>(xbf, W3, (void*)qkv, 8192, 3072, 1024);

  chunk_prep<<<dim3(2048), dim3(256), 0, stream>>>(qkv, a_raw, b_raw, Ub, Wb, SLb);
  chunk_scan<<<dim3(256), dim3(256), 0, stream>>>(qkv, Ub, Wb, SLb, state, xbf, state_out);

  gemm_bt<0><<<dim3(1024 / 128, 8192 / 128), dim3(256), 0, stream>>>(xbf, Wp, (void*)out, 8192, 1024, 1024);
}

// Round 6
// 211.458 us; speedup vs baseline: 4.1213x; 1.0017x over previous
//
#include <hip/hip_runtime.h>
#include <hip/hip_bf16.h>
#include <cstdint>

#define B_ 4
#define T_ 2048
#define C_ 1024
#define H_ 16
#define D_ 64
#define NC_ 32   // chunks
#define L_ 64    // chunk length

typedef __attribute__((ext_vector_type(8))) short bf16x8;
typedef __attribute__((ext_vector_type(4))) float f32x4;

static __device__ __forceinline__ unsigned short f2bf(float f) {
  unsigned u = __float_as_uint(f);
  u += 0x7fff + ((u >> 16) & 1);   // round-to-nearest-even
  return (unsigned short)(u >> 16);
}
static __device__ __forceinline__ float bf2f(unsigned short b) {
  return __uint_as_float(((unsigned)b) << 16);
}
// XOR swizzle for 128B-stride LDS rows (T2): keeps 16B alignment, <=2-way conflicts
static __device__ __forceinline__ int swz128(int row, int byte) {
  return row * 128 + (byte ^ ((row & 7) << 4));
}

// Barrier that does NOT drain vmcnt: LDS edges fenced via lgkmcnt(0); global
// prefetch loads stay in flight across it (T4). __syncthreads would emit
// s_waitcnt vmcnt(0) and expose the full HBM latency every chunk.
#define LDS_BARRIER() asm volatile("s_waitcnt lgkmcnt(0)\ns_barrier" ::: "memory")

// ---------------- f32 -> bf16 convert ----------------
__global__ __launch_bounds__(256) void cvt_kernel(const float* __restrict__ src,
                                                  unsigned short* __restrict__ dst, int n) {
  int i = (blockIdx.x * 256 + threadIdx.x) * 4;
  if (i >= n) return;
  float4 v = *reinterpret_cast<const float4*>(src + i);
  ushort4 o;
  o.x = f2bf(v.x); o.y = f2bf(v.y); o.z = f2bf(v.z); o.w = f2bf(v.w);
  *reinterpret_cast<ushort4*>(dst + i) = o;
}

// 4 weight matrices in one launch
__global__ __launch_bounds__(256) void cvt_w_kernel(const float* __restrict__ wq,
                                                    const float* __restrict__ wk,
                                                    const float* __restrict__ wv,
                                                    const float* __restrict__ wp,
                                                    unsigned short* __restrict__ W3,
                                                    unsigned short* __restrict__ Wp) {
  const int g = blockIdx.x >> 10;
  const float* src = (g == 0) ? wq : (g == 1) ? wk : (g == 2) ? wv : wp;
  unsigned short* dst = (g < 3) ? (W3 + (long)g * 1048576) : Wp;
  int i = ((blockIdx.x & 1023) * 256 + threadIdx.x) * 4;
  float4 v = *reinterpret_cast<const float4*>(src + i);
  ushort4 o;
  o.x = f2bf(v.x); o.y = f2bf(v.y); o.z = f2bf(v.z); o.w = f2bf(v.w);
  *reinterpret_cast<ushort4*>(dst + i) = o;
}

// ---------------- bf16 GEMM: C[M,N] = A[M,K] * B[N,K]^T ----------------
template<int OUT_BF16>
__global__ __launch_bounds__(256) void gemm_bt(const unsigned short* __restrict__ A,
                                               const unsigned short* __restrict__ Bw,
                                               void* __restrict__ Cp,
                                               int M, int N, int K) {
  __shared__ __align__(16) unsigned short sA[128 * 32];
  __shared__ __align__(16) unsigned short sB[128 * 32];
  const int tid = threadIdx.x;
  const int wid = tid >> 6, lane = tid & 63;
  const int wm = wid >> 1, wn = wid & 1;
  const long blockM = (long)blockIdx.y * 128;
  const long blockN = (long)blockIdx.x * 128;

  f32x4 acc[4][4] = {};

  const int ar = lane >> 2;
  const int ac = (lane & 3) * 8;
  const unsigned short* Abase = A + (blockM + wid * 32 + ar) * (long)K + ac;
  const unsigned short* Bbase = Bw + (blockN + wid * 32 + ar) * (long)K + ac;
  char* sAb = (char*)sA + wid * 2048;
  char* sBb = (char*)sB + wid * 2048;

  for (int k0 = 0; k0 < K; k0 += 32) {
    __syncthreads();
    __builtin_amdgcn_global_load_lds((const __attribute__((address_space(1))) void*)(Abase + k0),
                                     (__attribute__((address_space(3))) void*)(sAb), 16, 0, 0);
    __builtin_amdgcn_global_load_lds((const __attribute__((address_space(1))) void*)(Abase + 16 * (long)K + k0),
                                     (__attribute__((address_space(3))) void*)(sAb + 1024), 16, 0, 0);
    __builtin_amdgcn_global_load_lds((const __attribute__((address_space(1))) void*)(Bbase + k0),
                                     (__attribute__((address_space(3))) void*)(sBb), 16, 0, 0);
    __builtin_amdgcn_global_load_lds((const __attribute__((address_space(1))) void*)(Bbase + 16 * (long)K + k0),
                                     (__attribute__((address_space(3))) void*)(sBb + 1024), 16, 0, 0);
    __syncthreads();

    const int koff = (lane >> 4) * 8;
    const int rA = wm * 64 + (lane & 15);
    const int rB = wn * 64 + (lane & 15);
    bf16x8 af[4], bfr[4];
#pragma unroll
    for (int m = 0; m < 4; ++m)
      af[m] = *reinterpret_cast<const bf16x8*>(&sA[(rA + m * 16) * 32 + koff]);
#pragma unroll
    for (int n = 0; n < 4; ++n)
      bfr[n] = *reinterpret_cast<const bf16x8*>(&sB[(rB + n * 16) * 32 + koff]);
#pragma unroll
    for (int m = 0; m < 4; ++m)
#pragma unroll
      for (int n = 0; n < 4; ++n)
        acc[m][n] = __builtin_amdgcn_mfma_f32_16x16x32_bf16(af[m], bfr[n], acc[m][n], 0, 0, 0);
  }

  const int cr = (lane >> 4) * 4;
  const int cc = lane & 15;
#pragma unroll
  for (int m = 0; m < 4; ++m) {
    long R = blockM + wm * 64 + m * 16 + cr;
#pragma unroll
    for (int n = 0; n < 4; ++n) {
      long Cc = blockN + wn * 64 + n * 16 + cc;
#pragma unroll
      for (int r = 0; r < 4; ++r) {
        if (OUT_BF16)
          ((unsigned short*)Cp)[(R + r) * (long)N + Cc] = f2bf(acc[m][n][r]);
        else
          ((float*)Cp)[(R + r) * (long)N + Cc] = acc[m][n][r];
      }
    }
  }
}

// ---------------- phase 1: per (bh, chunk) WY precompute ----------------
__global__ __launch_bounds__(256) void chunk_prep(
    unsigned short* __restrict__ qkv,
    const float* __restrict__ a_raw, const float* __restrict__ b_raw,
    unsigned short* __restrict__ Ubuf, unsigned short* __restrict__ Wbuf,
    unsigned short* __restrict__ SLbuf) {
  __shared__ __align__(16) unsigned short sK[64 * 64];  // swizzled [t][e]
  __shared__ __align__(16) unsigned short sQ[64 * 64];  // swizzled [t][e]
  __shared__ __align__(16) unsigned short sV[64 * 64];  // linear   [t][e]
  __shared__ float sA[64 * 64];                         // linear   [t][j]

  const int blk = blockIdx.x;           // bh*32 + c
  const int bh = blk >> 5, c = blk & 31;
  const int b = bh >> 4, h = bh & 15;
  const int tid = threadIdx.x;
  const int wid = tid >> 6, lane = tid & 63;

  const float alpha = 0.5f / (1.f + __expf(-a_raw[h]));
  const float beta  = 0.5f / (1.f + __expf(-b_raw[h]));

  {
    const int row = tid >> 2, cg = tid & 3;
    unsigned short* gp = qkv + (long)(b * 2048 + c * 64 + row) * 3072 + h * 64 + cg * 16;
    bf16x8 q0 = *(const bf16x8*)(gp);
    bf16x8 q1 = *(const bf16x8*)(gp + 8);
    bf16x8 k0 = *(const bf16x8*)(gp + 1024);
    bf16x8 k1 = *(const bf16x8*)(gp + 1024 + 8);
    bf16x8 v0 = *(const bf16x8*)(gp + 2048);
    bf16x8 v1 = *(const bf16x8*)(gp + 2048 + 8);
    float kf[16];
    float ss = 0.f;
#pragma unroll
    for (int i = 0; i < 8; ++i) { kf[i] = bf2f((unsigned short)k0[i]); ss += kf[i] * kf[i]; }
#pragma unroll
    for (int i = 0; i < 8; ++i) { kf[8 + i] = bf2f((unsigned short)k1[i]); ss += kf[8 + i] * kf[8 + i]; }
    ss += __shfl_xor(ss, 1);
    ss += __shfl_xor(ss, 2);
    const float inv = 1.f / fmaxf(sqrtf(ss), 1e-12f);
    bf16x8 n0, n1;
#pragma unroll
    for (int i = 0; i < 8; ++i) { n0[i] = (short)f2bf(kf[i] * inv); n1[i] = (short)f2bf(kf[8 + i] * inv); }
    *(bf16x8*)((char*)sK + swz128(row, cg * 32)) = n0;
    *(bf16x8*)((char*)sK + swz128(row, cg * 32 + 16)) = n1;
    *(bf16x8*)(gp + 1024) = n0;          // write normalized k back for phase 2
    *(bf16x8*)(gp + 1024 + 8) = n1;
    *(bf16x8*)((char*)sQ + swz128(row, cg * 32)) = q0;
    *(bf16x8*)((char*)sQ + swz128(row, cg * 32 + 16)) = q1;
    *(bf16x8*)((char*)sV + row * 128 + cg * 32) = v0;
    *(bf16x8*)((char*)sV + row * 128 + cg * 32 + 16) = v1;
  }
  __syncthreads();

  const int rfrag = lane & 15, koff = (lane >> 4) * 8, crow = (lane >> 4) * 4;
  const int w2 = wid & 1;
  if (wid < 2) {
    // A = K K^T (f32 to LDS)
#pragma unroll
    for (int mt = 0; mt < 2; ++mt) {
      const int m = w2 * 2 + mt;
      const int ra = 16 * m + rfrag;
      f32x4 acc[4] = {};
#pragma unroll
      for (int ks = 0; ks < 2; ++ks) {
        bf16x8 af = *(const bf16x8*)((const char*)sK + swz128(ra, ks * 64 + koff * 2));
#pragma unroll
        for (int n = 0; n < 4; ++n) {
          bf16x8 bf = *(const bf16x8*)((const char*)sK + swz128(16 * n + rfrag, ks * 64 + koff * 2));
          acc[n] = __builtin_amdgcn_mfma_f32_16x16x32_bf16(af, bf, acc[n], 0, 0, 0);
        }
      }
#pragma unroll
      for (int n = 0; n < 4; ++n)
#pragma unroll
        for (int r = 0; r < 4; ++r)
          sA[(16 * m + crow + r) * 64 + 16 * n + rfrag] = acc[n][r];
    }
  } else {
    // SL = stril(Q K^T) -> global bf16
#pragma unroll
    for (int mt = 0; mt < 2; ++mt) {
      const int m = w2 * 2 + mt;
      const int ra = 16 * m + rfrag;
      f32x4 acc[4] = {};
#pragma unroll
      for (int ks = 0; ks < 2; ++ks) {
        bf16x8 af = *(const bf16x8*)((const char*)sQ + swz128(ra, ks * 64 + koff * 2));
#pragma unroll
        for (int n = 0; n < 4; ++n) {
          bf16x8 bf = *(const bf16x8*)((const char*)sK + swz128(16 * n + rfrag, ks * 64 + koff * 2));
          acc[n] = __builtin_amdgcn_mfma_f32_16x16x32_bf16(af, bf, acc[n], 0, 0, 0);
        }
      }
#pragma unroll
      for (int n = 0; n < 4; ++n)
#pragma unroll
        for (int r = 0; r < 4; ++r) {
          int t = 16 * m + crow + r, j = 16 * n + rfrag;
          SLbuf[(long)blk * 4096 + t * 64 + j] = (j < t) ? f2bf(acc[n][r]) : (unsigned short)0;
        }
    }
  }
  __syncthreads();

  // forward substitution: x_t = rhs_t - alpha * sum_{j<t} A[t][j] x_j
  if (wid < 2) {
    const int d = lane;
    float x[64];
#pragma unroll
    for (int t = 0; t < 64; ++t) {
      float rhs;
      if (wid == 0) rhs = beta * bf2f(sV[t * 64 + d]);
      else          rhs = alpha * bf2f(*(const unsigned short*)((const char*)sK + swz128(t, 2 * d)));
      float s = 0.f;
#pragma unroll
      for (int j = 0; j < t; ++j) s = fmaf(sA[t * 64 + j], x[j], s);
      x[t] = rhs - alpha * s;
    }
    unsigned short* ob = (wid == 0 ? Ubuf : Wbuf) + (long)blk * 4096 + d;
#pragma unroll
    for (int t = 0; t < 64; ++t) ob[t * 64] = f2bf(x[t]);
  }
}

// ---------------- phase 2: sequential chunk recurrence (pure MFMA) ----------------
// per chunk: G = U - W*S^T ; Y = Q*S^T + SL*G ; S += G^T * K
// Grid: 256 blocks = (b,h) x 4 d-quarters. LDS_BARRIER (no vmcnt drain) lets
// the next-chunk prefetch loads stay in flight across all 3 barriers.
__global__ __launch_bounds__(256) void chunk_scan(
    const unsigned short* __restrict__ qkv,
    const unsigned short* __restrict__ Ubuf, const unsigned short* __restrict__ Wbuf,
    const unsigned short* __restrict__ SLbuf,
    const float* __restrict__ state_in, unsigned short* __restrict__ ybuf,
    float* __restrict__ state_out) {
  __shared__ __align__(16) unsigned short sQ[64 * 64];   // [t][e] swz
  __shared__ __align__(16) unsigned short sW[64 * 64];   // [t][e] swz
  __shared__ __align__(16) unsigned short sSL[64 * 64];  // [t][j] swz
  __shared__ __align__(16) unsigned short sKT[64 * 64];  // [e][t] swz (K transposed)
  __shared__ __align__(16) unsigned short sU[64 * 16];   // [t][dl] linear (this d-quarter)
  __shared__ __align__(16) unsigned short sGT[16 * 64];  // [dl][t] swz
  __shared__ __align__(16) unsigned short sS[16 * 64];   // [dl][e] swz (bf16 state quarter)

  const int blk = blockIdx.x;          // bh*4 + dq
  const int bh = blk >> 2, dq = blk & 3;
  const int b = bh >> 4, h = bh & 15;
  const int tid = threadIdx.x, wid = tid >> 6, lane = tid & 63;
  const int rfrag = lane & 15, koff = (lane >> 4) * 8, crow = (lane >> 4) * 4;
  const int row = tid >> 2, cg = tid & 3;

  const unsigned short* gpb = qkv + (long)(b * 2048 + row) * 3072 + h * 64 + cg * 16;
  const long tbb = ((long)(bh * 32) * 64 + row) * 64 + cg * 16;
  const long ubb = ((long)(bh * 32) * 64 + (tid >> 1)) * 64 + dq * 16 + (tid & 1) * 8;

  // prefetch chunk 0 into registers
  bf16x8 qv0, qv1, kv0, kv1, wv0, wv1, sl0, sl1, uv;
  {
    qv0 = *(const bf16x8*)gpb;
    qv1 = *(const bf16x8*)(gpb + 8);
    kv0 = *(const bf16x8*)(gpb + 1024);
    kv1 = *(const bf16x8*)(gpb + 1024 + 8);
    wv0 = *(const bf16x8*)(Wbuf + tbb);
    wv1 = *(const bf16x8*)(Wbuf + tbb + 8);
    sl0 = *(const bf16x8*)(SLbuf + tbb);
    sl1 = *(const bf16x8*)(SLbuf + tbb + 8);
    uv = (tid < 128) ? *(const bf16x8*)(Ubuf + ubb) : bf16x8{};
  }

  // persistent S quarter: wave wid owns e-cols [16*wid, 16*wid+16)
  f32x4 sacc;
#pragma unroll
  for (int r = 0; r < 4; ++r)
    sacc[r] = state_in[(long)bh * 4096 + (dq * 16 + crow + r) * 64 + 16 * wid + rfrag];
#pragma unroll
  for (int r = 0; r < 4; ++r)
    *(unsigned short*)((char*)sS + swz128(crow + r, 2 * (16 * wid + rfrag))) = f2bf(sacc[r]);

  for (int c = 0; c < NC_; ++c) {
    // ---- write prefetched tiles to LDS ----
    *(bf16x8*)((char*)sQ + swz128(row, cg * 32)) = qv0;
    *(bf16x8*)((char*)sQ + swz128(row, cg * 32 + 16)) = qv1;
    *(bf16x8*)((char*)sW + swz128(row, cg * 32)) = wv0;
    *(bf16x8*)((char*)sW + swz128(row, cg * 32 + 16)) = wv1;
    *(bf16x8*)((char*)sSL + swz128(row, cg * 32)) = sl0;
    *(bf16x8*)((char*)sSL + swz128(row, cg * 32 + 16)) = sl1;
#pragma unroll
    for (int i = 0; i < 8; ++i) {
      *(unsigned short*)((char*)sKT + swz128(cg * 16 + i, 2 * row)) = (unsigned short)kv0[i];
      *(unsigned short*)((char*)sKT + swz128(cg * 16 + 8 + i, 2 * row)) = (unsigned short)kv1[i];
    }
    if (tid < 128) *(bf16x8*)((char*)sU + ((tid >> 1) * 16 + (tid & 1) * 8) * 2) = uv;

    // ---- issue next chunk's global loads (stay in flight across barriers) ----
    {
      const int cn = (c + 1 < NC_) ? c + 1 : c;
      const unsigned short* gp = gpb + (long)cn * 64 * 3072;
      const long tb = tbb + (long)cn * 4096;
      qv0 = *(const bf16x8*)gp;
      qv1 = *(const bf16x8*)(gp + 8);
      kv0 = *(const bf16x8*)(gp + 1024);
      kv1 = *(const bf16x8*)(gp + 1024 + 8);
      wv0 = *(const bf16x8*)(Wbuf + tb);
      wv1 = *(const bf16x8*)(Wbuf + tb + 8);
      sl0 = *(const bf16x8*)(SLbuf + tb);
      sl1 = *(const bf16x8*)(SLbuf + tb + 8);
      if (tid < 128) uv = *(const bf16x8*)(Ubuf + ubb + (long)cn * 4096);
    }
    LDS_BARRIER();   // #1

    // stage A: P1 = W*S^T, Yacc = Q*S^T  (wave wid = t-tile m; n = dl quarter)
    const int ta = 16 * wid + rfrag;
    f32x4 p = {};
    f32x4 yac = {};
#pragma unroll
    for (int ks = 0; ks < 2; ++ks) {
      bf16x8 afw = *(const bf16x8*)((const char*)sW + swz128(ta, ks * 64 + koff * 2));
      bf16x8 afq = *(const bf16x8*)((const char*)sQ + swz128(ta, ks * 64 + koff * 2));
      bf16x8 bS = *(const bf16x8*)((const char*)sS + swz128(rfrag, ks * 64 + koff * 2));
      p = __builtin_amdgcn_mfma_f32_16x16x32_bf16(afw, bS, p, 0, 0, 0);
      yac = __builtin_amdgcn_mfma_f32_16x16x32_bf16(afq, bS, yac, 0, 0, 0);
    }
    // G = U - P1 -> GT (transposed, bf16)
#pragma unroll
    for (int r = 0; r < 4; ++r) {
      int t = 16 * wid + crow + r;
      float g = bf2f(sU[t * 16 + rfrag]) - p[r];
      *(unsigned short*)((char*)sGT + swz128(rfrag, 2 * t)) = f2bf(g);
    }
    LDS_BARRIER();   // #2

    // stage B: Y += SL*G ; S += G^T*K
#pragma unroll
    for (int ks = 0; ks < 2; ++ks) {
      bf16x8 aSL = *(const bf16x8*)((const char*)sSL + swz128(ta, ks * 64 + koff * 2));
      bf16x8 bGT = *(const bf16x8*)((const char*)sGT + swz128(rfrag, ks * 64 + koff * 2));
      yac = __builtin_amdgcn_mfma_f32_16x16x32_bf16(aSL, bGT, yac, 0, 0, 0);
    }
#pragma unroll
    for (int r = 0; r < 4; ++r) {
      int t = 16 * wid + crow + r;
      ybuf[(long)(b * 2048 + c * 64 + t) * 1024 + h * 64 + dq * 16 + rfrag] = f2bf(yac[r]);
    }
#pragma unroll
    for (int ks = 0; ks < 2; ++ks) {
      bf16x8 aGT = *(const bf16x8*)((const char*)sGT + swz128(rfrag, ks * 64 + koff * 2));
      bf16x8 bKT = *(const bf16x8*)((const char*)sKT + swz128(16 * wid + rfrag, ks * 64 + koff * 2));
      sacc = __builtin_amdgcn_mfma_f32_16x16x32_bf16(aGT, bKT, sacc, 0, 0, 0);
    }
    LDS_BARRIER();   // #3

    // refresh bf16 state quarter (consumed by stage A after next top barrier)
#pragma unroll
    for (int r = 0; r < 4; ++r)
      *(unsigned short*)((char*)sS + swz128(crow + r, 2 * (16 * wid + rfrag))) = f2bf(sacc[r]);
  }

#pragma unroll
  for (int r = 0; r < 4; ++r)
    state_out[(long)bh * 4096 + (dq * 16 + crow + r) * 64 + 16 * wid + rfrag] = sacc[r];
}

// ---------------- launch ----------------
extern "C" void kernel_launch(void* const* d_in, const int* in_sizes, int n_in,
                              void* d_out, int out_size, void* d_ws, size_t ws_size,
                              hipStream_t stream) {
  (void)in_sizes; (void)n_in; (void)out_size; (void)ws_size;
  const float* x     = (const float*)d_in[0];
  const float* Wq    = (const float*)d_in[1];
  const float* Wk    = (const float*)d_in[2];
  const float* Wv    = (const float*)d_in[3];
  const float* Wproj = (const float*)d_in[4];
  const float* a_raw = (const float*)d_in[5];
  const float* b_raw = (const float*)d_in[6];
  const float* state = (const float*)d_in[7];

  char* ws = (char*)d_ws;
  unsigned short* xbf = (unsigned short*)ws;                    // 16MB; reused as y
  unsigned short* W3  = (unsigned short*)(ws + (16l << 20));    // 6MB [Wq;Wk;Wv]
  unsigned short* Wp  = (unsigned short*)(ws + (22l << 20));    // 2MB
  unsigned short* qkv = (unsigned short*)(ws + (24l << 20));    // 48MB
  unsigned short* Ub  = (unsigned short*)(ws + (72l << 20));    // 16MB
  unsigned short* Wb  = (unsigned short*)(ws + (88l << 20));    // 16MB
  unsigned short* SLb = (unsigned short*)(ws + (104l << 20));   // 16MB -> 120MB total
  float* out = (float*)d_out;
  float* state_out = out + (long)B_ * T_ * C_;

  cvt_kernel<<<dim3(8192), dim3(256), 0, stream>>>(x, xbf, 8388608);
  cvt_w_kernel<<<dim3(4096), dim3(256), 0, stream>>>(Wq, Wk, Wv, Wproj, W3, Wp);

  gemm_bt<1><<<dim3(3072 / 128, 8192 / 128), dim3(256), 0, stream>>>(xbf, W3, (void*)qkv, 8192, 3072, 1024);

  chunk_prep<<<dim3(2048), dim3(256), 0, stream>>>(qkv, a_raw, b_raw, Ub, Wb, SLb);
  chunk_scan<<<dim3(256), dim3(256), 0, stream>>>(qkv, Ub, Wb, SLb, state, xbf, state_out);

  gemm_bt<0><<<dim3(1024 / 128, 8192 / 128), dim3(256), 0, stream>>>(xbf, Wp, (void*)out, 8192, 1024, 1024);
}

// Round 7
// 209.495 us; speedup vs baseline: 4.1599x; 1.0094x over previous
//
#include <hip/hip_runtime.h>
#include <hip/hip_bf16.h>
#include <cstdint>

#define B_ 4
#define T_ 2048
#define C_ 1024
#define H_ 16
#define D_ 64
#define NC_ 32   // chunks
#define L_ 64    // chunk length

typedef __attribute__((ext_vector_type(8))) short bf16x8;
typedef __attribute__((ext_vector_type(4))) float f32x4;

static __device__ __forceinline__ unsigned short f2bf(float f) {
  unsigned u = __float_as_uint(f);
  u += 0x7fff + ((u >> 16) & 1);   // round-to-nearest-even
  return (unsigned short)(u >> 16);
}
static __device__ __forceinline__ float bf2f(unsigned short b) {
  return __uint_as_float(((unsigned)b) << 16);
}
// XOR swizzle for 128B-stride LDS rows (T2): keeps 16B alignment, <=2-way conflicts
static __device__ __forceinline__ int swz128(int row, int byte) {
  return row * 128 + (byte ^ ((row & 7) << 4));
}

// Barrier that does NOT drain vmcnt (T4): LDS edges fenced via lgkmcnt(0).
#define LDS_BARRIER() asm volatile("s_waitcnt lgkmcnt(0)\ns_barrier" ::: "memory")

// ---------------- f32 -> bf16 convert ----------------
__global__ __launch_bounds__(256) void cvt_kernel(const float* __restrict__ src,
                                                  unsigned short* __restrict__ dst, int n) {
  int i = (blockIdx.x * 256 + threadIdx.x) * 4;
  if (i >= n) return;
  float4 v = *reinterpret_cast<const float4*>(src + i);
  ushort4 o;
  o.x = f2bf(v.x); o.y = f2bf(v.y); o.z = f2bf(v.z); o.w = f2bf(v.w);
  *reinterpret_cast<ushort4*>(dst + i) = o;
}

// 4 weight matrices in one launch
__global__ __launch_bounds__(256) void cvt_w_kernel(const float* __restrict__ wq,
                                                    const float* __restrict__ wk,
                                                    const float* __restrict__ wv,
                                                    const float* __restrict__ wp,
                                                    unsigned short* __restrict__ W3,
                                                    unsigned short* __restrict__ Wp) {
  const int g = blockIdx.x >> 10;
  const float* src = (g == 0) ? wq : (g == 1) ? wk : (g == 2) ? wv : wp;
  unsigned short* dst = (g < 3) ? (W3 + (long)g * 1048576) : Wp;
  int i = ((blockIdx.x & 1023) * 256 + threadIdx.x) * 4;
  float4 v = *reinterpret_cast<const float4*>(src + i);
  ushort4 o;
  o.x = f2bf(v.x); o.y = f2bf(v.y); o.z = f2bf(v.z); o.w = f2bf(v.w);
  *reinterpret_cast<ushort4*>(dst + i) = o;
}

// ================= 8-phase 256x256 bf16 GEMM (T3+T4+T5, swizzled LDS) ==========
// C[M,N] = A[M,K] * B[N,K]^T, K=1024 fixed, M%256==0, N%256==0, bf16 out.
// 512 thr / 8 waves (2M x 4N, interleaved ownership). BK=64, 2 K-tiles/iter,
// 8 phases/iter: {vmcnt(6); 12 ds_read_b128; stage 1 half-tile (2x
// global_load_lds w16); barrier; lgkmcnt(0); 16 MFMA (setprio); barrier}.
// LDS: linear [256][64] per region with 16B-block involution kb^=(row&7),
// applied on read addr and pre-applied on per-lane global source (rule #21).

#define STAGE256(GP, GR0, KT, LOFF) do {                                          \
    const unsigned short* _s = (GP) + ((GR0) + wid * 8 + lr8) * 1024L             \
                               + (long)(KT) * 64 + skb * 8;                       \
    char* _d = (char*)lds + (LOFF) + wid * 1024;                                  \
    __builtin_amdgcn_global_load_lds((const __attribute__((address_space(1))) void*)_s,      \
        (__attribute__((address_space(3))) void*)_d, 16, 0, 0);                   \
    __builtin_amdgcn_global_load_lds((const __attribute__((address_space(1))) void*)(_s + 64 * 1024L), \
        (__attribute__((address_space(3))) void*)(_d + 8192), 16, 0, 0);          \
  } while (0)

#define PHASE256(AO, BO, MH, NH, STG) do {                                        \
    asm volatile("s_waitcnt vmcnt(6)" ::: "memory");                              \
    bf16x8 av[4][2], bv[2][2];                                                    \
    {                                                                             \
      const char* ab = (const char*)lds + (AO) + (MH) * 16384 + arow;             \
      const char* bb = (const char*)lds + (BO) + (NH) * 16384 + brow;             \
      _Pragma("unroll")                                                           \
      for (int j = 0; j < 4; ++j) {                                               \
        av[j][0] = *(const bf16x8*)(ab + j * 4096 + cb0);                         \
        av[j][1] = *(const bf16x8*)(ab + j * 4096 + cb1);                         \
      }                                                                           \
      _Pragma("unroll")                                                           \
      for (int j2 = 0; j2 < 2; ++j2) {                                            \
        bv[j2][0] = *(const bf16x8*)(bb + j2 * 8192 + cb0);                       \
        bv[j2][1] = *(const bf16x8*)(bb + j2 * 8192 + cb1);                       \
      }                                                                           \
    }                                                                             \
    STG;                                                                          \
    __builtin_amdgcn_s_barrier();                                                 \
    asm volatile("s_waitcnt lgkmcnt(0)" ::: "memory");                            \
    __builtin_amdgcn_sched_barrier(0);                                            \
    __builtin_amdgcn_s_setprio(1);                                                \
    _Pragma("unroll")                                                             \
    for (int j = 0; j < 4; ++j)                                                   \
      _Pragma("unroll")                                                           \
      for (int j2 = 0; j2 < 2; ++j2)                                              \
        acc[(MH) * 4 + j][(NH) * 2 + j2] = __builtin_amdgcn_mfma_f32_16x16x32_bf16( \
            av[j][0], bv[j2][0], acc[(MH) * 4 + j][(NH) * 2 + j2], 0, 0, 0);      \
    _Pragma("unroll")                                                             \
    for (int j = 0; j < 4; ++j)                                                   \
      _Pragma("unroll")                                                           \
      for (int j2 = 0; j2 < 2; ++j2)                                              \
        acc[(MH) * 4 + j][(NH) * 2 + j2] = __builtin_amdgcn_mfma_f32_16x16x32_bf16( \
            av[j][1], bv[j2][1], acc[(MH) * 4 + j][(NH) * 2 + j2], 0, 0, 0);      \
    __builtin_amdgcn_s_setprio(0);                                                \
    __builtin_amdgcn_s_barrier();                                                 \
  } while (0)

__global__ __launch_bounds__(512, 2) void gemm256_bt(
    const unsigned short* __restrict__ A,
    const unsigned short* __restrict__ Bw,
    unsigned short* __restrict__ C, int N) {
  __shared__ __align__(16) char lds[131072];
  // regions (bytes): evenA 0, evenB 32768, oddA 65536, oddB 98304; half = +16384
  enum { EA = 0, EB = 32768, OA = 65536, OB = 98304, HF = 16384 };
  const int tid = threadIdx.x;
  const int wid = tid >> 6, lane = tid & 63;
  const int wm = wid >> 2, wn = wid & 3;
  const int f = lane & 15, g = lane >> 4;
  const int lr8 = lane >> 3, lc = lane & 7;
  const int skb = lc ^ lr8;                 // pre-swizzled source col-block
  const long bM = (long)blockIdx.y * 256;
  const long bN = (long)blockIdx.x * 256;
  const int cb0 = ((0 + g) ^ (f & 7)) * 16; // ks=0 read col-byte (swizzled)
  const int cb1 = ((4 + g) ^ (f & 7)) * 16; // ks=1
  const int arow = (wm * 16 + f) * 128;
  const int brow = (wn * 16 + f) * 128;

  f32x4 acc[8][4] = {};

  // prologue: stage tile0 (Aa0,Ab0,Aa1,Ab1) + tile1 h0 (Bb0,Ba0); sync cross-wave
  STAGE256(A, bM, 0, EA);
  STAGE256(Bw, bN, 0, EB);
  STAGE256(A, bM + 128, 0, EA + HF);
  STAGE256(Bw, bN + 128, 0, EB + HF);
  STAGE256(Bw, bN, 1, OB);
  STAGE256(A, bM, 1, OA);
  asm volatile("s_waitcnt vmcnt(8)" ::: "memory");  // Aa0,Ab0 landed (first 4 loads)
  __builtin_amdgcn_s_barrier();

  for (int i = 0; i < 8; ++i) {
    const int todd = 2 * i + 1;
    int te = 2 * i + 2; if (te > 14) te = 14;   // ghost-clamp keeps vmcnt uniform
    int to = 2 * i + 3; if (to > 15) to = 15;
    // phases 0-3: consume even buf (tile 2i); 4-7: odd buf (tile 2i+1)
    PHASE256(EA, EB, 0, 0, STAGE256(A, bM + 128, todd, OA + HF));
    PHASE256(EA, EB, 1, 0, STAGE256(Bw, bN + 128, todd, OB + HF));
    PHASE256(EA, EB, 0, 1, STAGE256(Bw, bN, te, EB));
    PHASE256(EA, EB, 1, 1, STAGE256(A, bM, te, EA));
    PHASE256(OA, OB, 0, 0, STAGE256(A, bM + 128, te, EA + HF));
    PHASE256(OA, OB, 1, 0, STAGE256(Bw, bN + 128, te, EB + HF));
    PHASE256(OA, OB, 0, 1, STAGE256(Bw, bN, to, OB));
    PHASE256(OA, OB, 1, 1, STAGE256(A, bM, to, OA));
  }

  // epilogue: interleaved wave ownership
#pragma unroll
  for (int mf = 0; mf < 8; ++mf) {
    long row = bM + (mf >> 2) * 128 + (mf & 3) * 32 + wm * 16 + g * 4;
#pragma unroll
    for (int nf = 0; nf < 4; ++nf) {
      long col = bN + (nf >> 1) * 128 + (nf & 1) * 64 + wn * 16 + f;
#pragma unroll
      for (int r = 0; r < 4; ++r)
        C[(row + r) * (long)N + col] = f2bf(acc[mf][nf][r]);
    }
  }
}

// ---------------- m97-style 128x128 GEMM (kept for gemm2) ----------------
template<int OUT_BF16>
__global__ __launch_bounds__(256) void gemm_bt(const unsigned short* __restrict__ A,
                                               const unsigned short* __restrict__ Bw,
                                               void* __restrict__ Cp,
                                               int M, int N, int K) {
  __shared__ __align__(16) unsigned short sA[128 * 32];
  __shared__ __align__(16) unsigned short sB[128 * 32];
  const int tid = threadIdx.x;
  const int wid = tid >> 6, lane = tid & 63;
  const int wm = wid >> 1, wn = wid & 1;
  const long blockM = (long)blockIdx.y * 128;
  const long blockN = (long)blockIdx.x * 128;

  f32x4 acc[4][4] = {};

  const int ar = lane >> 2;
  const int ac = (lane & 3) * 8;
  const unsigned short* Abase = A + (blockM + wid * 32 + ar) * (long)K + ac;
  const unsigned short* Bbase = Bw + (blockN + wid * 32 + ar) * (long)K + ac;
  char* sAb = (char*)sA + wid * 2048;
  char* sBb = (char*)sB + wid * 2048;

  for (int k0 = 0; k0 < K; k0 += 32) {
    __syncthreads();
    __builtin_amdgcn_global_load_lds((const __attribute__((address_space(1))) void*)(Abase + k0),
                                     (__attribute__((address_space(3))) void*)(sAb), 16, 0, 0);
    __builtin_amdgcn_global_load_lds((const __attribute__((address_space(1))) void*)(Abase + 16 * (long)K + k0),
                                     (__attribute__((address_space(3))) void*)(sAb + 1024), 16, 0, 0);
    __builtin_amdgcn_global_load_lds((const __attribute__((address_space(1))) void*)(Bbase + k0),
                                     (__attribute__((address_space(3))) void*)(sBb), 16, 0, 0);
    __builtin_amdgcn_global_load_lds((const __attribute__((address_space(1))) void*)(Bbase + 16 * (long)K + k0),
                                     (__attribute__((address_space(3))) void*)(sBb + 1024), 16, 0, 0);
    __syncthreads();

    const int koff = (lane >> 4) * 8;
    const int rA = wm * 64 + (lane & 15);
    const int rB = wn * 64 + (lane & 15);
    bf16x8 af[4], bfr[4];
#pragma unroll
    for (int m = 0; m < 4; ++m)
      af[m] = *reinterpret_cast<const bf16x8*>(&sA[(rA + m * 16) * 32 + koff]);
#pragma unroll
    for (int n = 0; n < 4; ++n)
      bfr[n] = *reinterpret_cast<const bf16x8*>(&sB[(rB + n * 16) * 32 + koff]);
#pragma unroll
    for (int m = 0; m < 4; ++m)
#pragma unroll
      for (int n = 0; n < 4; ++n)
        acc[m][n] = __builtin_amdgcn_mfma_f32_16x16x32_bf16(af[m], bfr[n], acc[m][n], 0, 0, 0);
  }

  const int cr = (lane >> 4) * 4;
  const int cc = lane & 15;
#pragma unroll
  for (int m = 0; m < 4; ++m) {
    long R = blockM + wm * 64 + m * 16 + cr;
#pragma unroll
    for (int n = 0; n < 4; ++n) {
      long Cc = blockN + wn * 64 + n * 16 + cc;
#pragma unroll
      for (int r = 0; r < 4; ++r) {
        if (OUT_BF16)
          ((unsigned short*)Cp)[(R + r) * (long)N + Cc] = f2bf(acc[m][n][r]);
        else
          ((float*)Cp)[(R + r) * (long)N + Cc] = acc[m][n][r];
      }
    }
  }
}

// ---------------- phase 1: per (bh, chunk) WY precompute ----------------
__global__ __launch_bounds__(256) void chunk_prep(
    unsigned short* __restrict__ qkv,
    const float* __restrict__ a_raw, const float* __restrict__ b_raw,
    unsigned short* __restrict__ Ubuf, unsigned short* __restrict__ Wbuf,
    unsigned short* __restrict__ SLbuf) {
  __shared__ __align__(16) unsigned short sK[64 * 64];  // swizzled [t][e]
  __shared__ __align__(16) unsigned short sQ[64 * 64];  // swizzled [t][e]
  __shared__ __align__(16) unsigned short sV[64 * 64];  // linear   [t][e]
  __shared__ float sA[64 * 64];                         // linear   [t][j]

  const int blk = blockIdx.x;           // bh*32 + c
  const int bh = blk >> 5, c = blk & 31;
  const int b = bh >> 4, h = bh & 15;
  const int tid = threadIdx.x;
  const int wid = tid >> 6, lane = tid & 63;

  const float alpha = 0.5f / (1.f + __expf(-a_raw[h]));
  const float beta  = 0.5f / (1.f + __expf(-b_raw[h]));

  {
    const int row = tid >> 2, cg = tid & 3;
    unsigned short* gp = qkv + (long)(b * 2048 + c * 64 + row) * 3072 + h * 64 + cg * 16;
    bf16x8 q0 = *(const bf16x8*)(gp);
    bf16x8 q1 = *(const bf16x8*)(gp + 8);
    bf16x8 k0 = *(const bf16x8*)(gp + 1024);
    bf16x8 k1 = *(const bf16x8*)(gp + 1024 + 8);
    bf16x8 v0 = *(const bf16x8*)(gp + 2048);
    bf16x8 v1 = *(const bf16x8*)(gp + 2048 + 8);
    float kf[16];
    float ss = 0.f;
#pragma unroll
    for (int i = 0; i < 8; ++i) { kf[i] = bf2f((unsigned short)k0[i]); ss += kf[i] * kf[i]; }
#pragma unroll
    for (int i = 0; i < 8; ++i) { kf[8 + i] = bf2f((unsigned short)k1[i]); ss += kf[8 + i] * kf[8 + i]; }
    ss += __shfl_xor(ss, 1);
    ss += __shfl_xor(ss, 2);
    const float inv = 1.f / fmaxf(sqrtf(ss), 1e-12f);
    bf16x8 n0, n1;
#pragma unroll
    for (int i = 0; i < 8; ++i) { n0[i] = (short)f2bf(kf[i] * inv); n1[i] = (short)f2bf(kf[8 + i] * inv); }
    *(bf16x8*)((char*)sK + swz128(row, cg * 32)) = n0;
    *(bf16x8*)((char*)sK + swz128(row, cg * 32 + 16)) = n1;
    *(bf16x8*)(gp + 1024) = n0;          // write normalized k back for phase 2
    *(bf16x8*)(gp + 1024 + 8) = n1;
    *(bf16x8*)((char*)sQ + swz128(row, cg * 32)) = q0;
    *(bf16x8*)((char*)sQ + swz128(row, cg * 32 + 16)) = q1;
    *(bf16x8*)((char*)sV + row * 128 + cg * 32) = v0;
    *(bf16x8*)((char*)sV + row * 128 + cg * 32 + 16) = v1;
  }
  __syncthreads();

  const int rfrag = lane & 15, koff = (lane >> 4) * 8, crow = (lane >> 4) * 4;
  const int w2 = wid & 1;
  if (wid < 2) {
    // A = K K^T (f32 to LDS)
#pragma unroll
    for (int mt = 0; mt < 2; ++mt) {
      const int m = w2 * 2 + mt;
      const int ra = 16 * m + rfrag;
      f32x4 acc[4] = {};
#pragma unroll
      for (int ks = 0; ks < 2; ++ks) {
        bf16x8 af = *(const bf16x8*)((const char*)sK + swz128(ra, ks * 64 + koff * 2));
#pragma unroll
        for (int n = 0; n < 4; ++n) {
          bf16x8 bf = *(const bf16x8*)((const char*)sK + swz128(16 * n + rfrag, ks * 64 + koff * 2));
          acc[n] = __builtin_amdgcn_mfma_f32_16x16x32_bf16(af, bf, acc[n], 0, 0, 0);
        }
      }
#pragma unroll
      for (int n = 0; n < 4; ++n)
#pragma unroll
        for (int r = 0; r < 4; ++r)
          sA[(16 * m + crow + r) * 64 + 16 * n + rfrag] = acc[n][r];
    }
  } else {
    // SL = stril(Q K^T) -> global bf16
#pragma unroll
    for (int mt = 0; mt < 2; ++mt) {
      const int m = w2 * 2 + mt;
      const int ra = 16 * m + rfrag;
      f32x4 acc[4] = {};
#pragma unroll
      for (int ks = 0; ks < 2; ++ks) {
        bf16x8 af = *(const bf16x8*)((const char*)sQ + swz128(ra, ks * 64 + koff * 2));
#pragma unroll
        for (int n = 0; n < 4; ++n) {
          bf16x8 bf = *(const bf16x8*)((const char*)sK + swz128(16 * n + rfrag, ks * 64 + koff * 2));
          acc[n] = __builtin_amdgcn_mfma_f32_16x16x32_bf16(af, bf, acc[n], 0, 0, 0);
        }
      }
#pragma unroll
      for (int n = 0; n < 4; ++n)
#pragma unroll
        for (int r = 0; r < 4; ++r) {
          int t = 16 * m + crow + r, j = 16 * n + rfrag;
          SLbuf[(long)blk * 4096 + t * 64 + j] = (j < t) ? f2bf(acc[n][r]) : (unsigned short)0;
        }
    }
  }
  __syncthreads();

  // forward substitution: x_t = rhs_t - alpha * sum_{j<t} A[t][j] x_j
  if (wid < 2) {
    const int d = lane;
    float x[64];
#pragma unroll
    for (int t = 0; t < 64; ++t) {
      float rhs;
      if (wid == 0) rhs = beta * bf2f(sV[t * 64 + d]);
      else          rhs = alpha * bf2f(*(const unsigned short*)((const char*)sK + swz128(t, 2 * d)));
      float s = 0.f;
#pragma unroll
      for (int j = 0; j < t; ++j) s = fmaf(sA[t * 64 + j], x[j], s);
      x[t] = rhs - alpha * s;
    }
    unsigned short* ob = (wid == 0 ? Ubuf : Wbuf) + (long)blk * 4096 + d;
#pragma unroll
    for (int t = 0; t < 64; ++t) ob[t * 64] = f2bf(x[t]);
  }
}

// ---------------- phase 2: sequential chunk recurrence (pure MFMA) ----------------
__global__ __launch_bounds__(256) void chunk_scan(
    const unsigned short* __restrict__ qkv,
    const unsigned short* __restrict__ Ubuf, const unsigned short* __restrict__ Wbuf,
    const unsigned short* __restrict__ SLbuf,
    const float* __restrict__ state_in, unsigned short* __restrict__ ybuf,
    float* __restrict__ state_out) {
  __shared__ __align__(16) unsigned short sQ[64 * 64];   // [t][e] swz
  __shared__ __align__(16) unsigned short sW[64 * 64];   // [t][e] swz
  __shared__ __align__(16) unsigned short sSL[64 * 64];  // [t][j] swz
  __shared__ __align__(16) unsigned short sKT[64 * 64];  // [e][t] swz (K transposed)
  __shared__ __align__(16) unsigned short sU[64 * 16];   // [t][dl] linear (this d-quarter)
  __shared__ __align__(16) unsigned short sGT[16 * 64];  // [dl][t] swz
  __shared__ __align__(16) unsigned short sS[16 * 64];   // [dl][e] swz (bf16 state quarter)

  const int blk = blockIdx.x;          // bh*4 + dq
  const int bh = blk >> 2, dq = blk & 3;
  const int b = bh >> 4, h = bh & 15;
  const int tid = threadIdx.x, wid = tid >> 6, lane = tid & 63;
  const int rfrag = lane & 15, koff = (lane >> 4) * 8, crow = (lane >> 4) * 4;
  const int row = tid >> 2, cg = tid & 3;

  const unsigned short* gpb = qkv + (long)(b * 2048 + row) * 3072 + h * 64 + cg * 16;
  const long tbb = ((long)(bh * 32) * 64 + row) * 64 + cg * 16;
  const long ubb = ((long)(bh * 32) * 64 + (tid >> 1)) * 64 + dq * 16 + (tid & 1) * 8;

  // prefetch chunk 0 into registers
  bf16x8 qv0, qv1, kv0, kv1, wv0, wv1, sl0, sl1, uv;
  {
    qv0 = *(const bf16x8*)gpb;
    qv1 = *(const bf16x8*)(gpb + 8);
    kv0 = *(const bf16x8*)(gpb + 1024);
    kv1 = *(const bf16x8*)(gpb + 1024 + 8);
    wv0 = *(const bf16x8*)(Wbuf + tbb);
    wv1 = *(const bf16x8*)(Wbuf + tbb + 8);
    sl0 = *(const bf16x8*)(SLbuf + tbb);
    sl1 = *(const bf16x8*)(SLbuf + tbb + 8);
    uv = (tid < 128) ? *(const bf16x8*)(Ubuf + ubb) : bf16x8{};
  }

  // persistent S quarter: wave wid owns e-cols [16*wid, 16*wid+16)
  f32x4 sacc;
#pragma unroll
  for (int r = 0; r < 4; ++r)
    sacc[r] = state_in[(long)bh * 4096 + (dq * 16 + crow + r) * 64 + 16 * wid + rfrag];
#pragma unroll
  for (int r = 0; r < 4; ++r)
    *(unsigned short*)((char*)sS + swz128(crow + r, 2 * (16 * wid + rfrag))) = f2bf(sacc[r]);

  for (int c = 0; c < NC_; ++c) {
    // ---- write prefetched tiles to LDS ----
    *(bf16x8*)((char*)sQ + swz128(row, cg * 32)) = qv0;
    *(bf16x8*)((char*)sQ + swz128(row, cg * 32 + 16)) = qv1;
    *(bf16x8*)((char*)sW + swz128(row, cg * 32)) = wv0;
    *(bf16x8*)((char*)sW + swz128(row, cg * 32 + 16)) = wv1;
    *(bf16x8*)((char*)sSL + swz128(row, cg * 32)) = sl0;
    *(bf16x8*)((char*)sSL + swz128(row, cg * 32 + 16)) = sl1;
#pragma unroll
    for (int i = 0; i < 8; ++i) {
      *(unsigned short*)((char*)sKT + swz128(cg * 16 + i, 2 * row)) = (unsigned short)kv0[i];
      *(unsigned short*)((char*)sKT + swz128(cg * 16 + 8 + i, 2 * row)) = (unsigned short)kv1[i];
    }
    if (tid < 128) *(bf16x8*)((char*)sU + ((tid >> 1) * 16 + (tid & 1) * 8) * 2) = uv;

    // ---- issue next chunk's global loads (stay in flight across barriers) ----
    {
      const int cn = (c + 1 < NC_) ? c + 1 : c;
      const unsigned short* gp = gpb + (long)cn * 64 * 3072;
      const long tb = tbb + (long)cn * 4096;
      qv0 = *(const bf16x8*)gp;
      qv1 = *(const bf16x8*)(gp + 8);
      kv0 = *(const bf16x8*)(gp + 1024);
      kv1 = *(const bf16x8*)(gp + 1024 + 8);
      wv0 = *(const bf16x8*)(Wbuf + tb);
      wv1 = *(const bf16x8*)(Wbuf + tb + 8);
      sl0 = *(const bf16x8*)(SLbuf + tb);
      sl1 = *(const bf16x8*)(SLbuf + tb + 8);
      if (tid < 128) uv = *(const bf16x8*)(Ubuf + ubb + (long)cn * 4096);
    }
    LDS_BARRIER();   // #1

    // stage A: P1 = W*S^T, Yacc = Q*S^T
    const int ta = 16 * wid + rfrag;
    f32x4 p = {};
    f32x4 yac = {};
#pragma unroll
    for (int ks = 0; ks < 2; ++ks) {
      bf16x8 afw = *(const bf16x8*)((const char*)sW + swz128(ta, ks * 64 + koff * 2));
      bf16x8 afq = *(const bf16x8*)((const char*)sQ + swz128(ta, ks * 64 + koff * 2));
      bf16x8 bS = *(const bf16x8*)((const char*)sS + swz128(rfrag, ks * 64 + koff * 2));
      p = __builtin_amdgcn_mfma_f32_16x16x32_bf16(afw, bS, p, 0, 0, 0);
      yac = __builtin_amdgcn_mfma_f32_16x16x32_bf16(afq, bS, yac, 0, 0, 0);
    }
    // G = U - P1 -> GT (transposed, bf16)
#pragma unroll
    for (int r = 0; r < 4; ++r) {
      int t = 16 * wid + crow + r;
      float gg = bf2f(sU[t * 16 + rfrag]) - p[r];
      *(unsigned short*)((char*)sGT + swz128(rfrag, 2 * t)) = f2bf(gg);
    }
    LDS_BARRIER();   // #2

    // stage B: Y += SL*G ; S += G^T*K
#pragma unroll
    for (int ks = 0; ks < 2; ++ks) {
      bf16x8 aSL = *(const bf16x8*)((const char*)sSL + swz128(ta, ks * 64 + koff * 2));
      bf16x8 bGT = *(const bf16x8*)((const char*)sGT + swz128(rfrag, ks * 64 + koff * 2));
      yac = __builtin_amdgcn_mfma_f32_16x16x32_bf16(aSL, bGT, yac, 0, 0, 0);
    }
#pragma unroll
    for (int r = 0; r < 4; ++r) {
      int t = 16 * wid + crow + r;
      ybuf[(long)(b * 2048 + c * 64 + t) * 1024 + h * 64 + dq * 16 + rfrag] = f2bf(yac[r]);
    }
#pragma unroll
    for (int ks = 0; ks < 2; ++ks) {
      bf16x8 aGT = *(const bf16x8*)((const char*)sGT + swz128(rfrag, ks * 64 + koff * 2));
      bf16x8 bKT = *(const bf16x8*)((const char*)sKT + swz128(16 * wid + rfrag, ks * 64 + koff * 2));
      sacc = __builtin_amdgcn_mfma_f32_16x16x32_bf16(aGT, bKT, sacc, 0, 0, 0);
    }
    LDS_BARRIER();   // #3

    // refresh bf16 state quarter
#pragma unroll
    for (int r = 0; r < 4; ++r)
      *(unsigned short*)((char*)sS + swz128(crow + r, 2 * (16 * wid + rfrag))) = f2bf(sacc[r]);
  }

#pragma unroll
  for (int r = 0; r < 4; ++r)
    state_out[(long)bh * 4096 + (dq * 16 + crow + r) * 64 + 16 * wid + rfrag] = sacc[r];
}

// ---------------- launch ----------------
extern "C" void kernel_launch(void* const* d_in, const int* in_sizes, int n_in,
                              void* d_out, int out_size, void* d_ws, size_t ws_size,
                              hipStream_t stream) {
  (void)in_sizes; (void)n_in; (void)out_size; (void)ws_size;
  const float* x     = (const float*)d_in[0];
  const float* Wq    = (const float*)d_in[1];
  const float* Wk    = (const float*)d_in[2];
  const float* Wv    = (const float*)d_in[3];
  const float* Wproj = (const float*)d_in[4];
  const float* a_raw = (const float*)d_in[5];
  const float* b_raw = (const float*)d_in[6];
  const float* state = (const float*)d_in[7];

  char* ws = (char*)d_ws;
  unsigned short* xbf = (unsigned short*)ws;                    // 16MB; reused as y
  unsigned short* W3  = (unsigned short*)(ws + (16l << 20));    // 6MB [Wq;Wk;Wv]
  unsigned short* Wp  = (unsigned short*)(ws + (22l << 20));    // 2MB
  unsigned short* qkv = (unsigned short*)(ws + (24l << 20));    // 48MB
  unsigned short* Ub  = (unsigned short*)(ws + (72l << 20));    // 16MB
  unsigned short* Wb  = (unsigned short*)(ws + (88l << 20));    // 16MB
  unsigned short* SLb = (unsigned short*)(ws + (104l << 20));   // 16MB -> 120MB total
  float* out = (float*)d_out;
  float* state_out = out + (long)B_ * T_ * C_;

  cvt_kernel<<<dim3(8192), dim3(256), 0, stream>>>(x, xbf, 8388608);
  cvt_w_kernel<<<dim3(4096), dim3(256), 0, stream>>>(Wq, Wk, Wv, Wproj, W3, Wp);

  // QKV projection: 8-phase 256^2 GEMM (M=8192, N=3072, K=1024)
  gemm256_bt<<<dim3(3072 / 256, 8192 / 256), dim3(512), 0, stream>>>(xbf, W3, qkv, 3072);

  chunk_prep<<<dim3(2048), dim3(256), 0, stream>>>(qkv, a_raw, b_raw, Ub, Wb, SLb);
  chunk_scan<<<dim3(256), dim3(256), 0, stream>>>(qkv, Ub, Wb, SLb, state, xbf, state_out);

  gemm_bt<0><<<dim3(1024 / 128, 8192 / 128), dim3(256), 0, stream>>>(xbf, Wp, (void*)out, 8192, 1024, 1024);
}